// Round 7
// baseline (251.393 us; speedup 1.0000x reference)
//
#include <hip/hip_runtime.h>
#include <hip/hip_bf16.h>

typedef __bf16 bf16_t;
typedef __bf16 bf16x8 __attribute__((ext_vector_type(8)));
typedef float f32x4 __attribute__((ext_vector_type(4)));
typedef unsigned int uint32x2 __attribute__((ext_vector_type(2)));
typedef unsigned int uint32x4 __attribute__((ext_vector_type(4)));

#define B_SZ 4
#define SEQ 2048
#define NH 16
#define DH 64
#define DM 1024
#define RSQ (3 * DM)

// async global->LDS, 16B per lane. LDS dest = wave-uniform base + lane*16.
__device__ __forceinline__ void gload_lds16(const bf16_t* g, bf16_t* l) {
  __builtin_amdgcn_global_load_lds(
      (const __attribute__((address_space(1))) unsigned int*)g,
      (__attribute__((address_space(3))) unsigned int*)l, 16, 0, 0);
}

__device__ __forceinline__ unsigned lds_b32addr(void* p) {
  return (unsigned)(uintptr_t)(__attribute__((address_space(3))) void*)p;
}

// ---------------------------------------------------------------------------
// fp32 -> bf16 elementwise convert, 4 elems/thread.
// ---------------------------------------------------------------------------
__global__ __launch_bounds__(256) void f32_to_bf16_kernel(
    const float* __restrict__ in, bf16_t* __restrict__ out, int n) {
  int i = (blockIdx.x * blockDim.x + threadIdx.x) * 4;
  if (i >= n) return;
  float4 v = *reinterpret_cast<const float4*>(in + i);
  bf16_t o[4] = {(bf16_t)v.x, (bf16_t)v.y, (bf16_t)v.z, (bf16_t)v.w};
  *reinterpret_cast<uint2*>(out + i) = *reinterpret_cast<const uint2*>(o);
}

// ---------------------------------------------------------------------------
// fp32 [K][N] -> bf16 transposed [N][K], output rows < scale_cols scaled.
// ---------------------------------------------------------------------------
__global__ __launch_bounds__(256) void transpose_f32_bf16_kernel(
    const float* __restrict__ in, bf16_t* __restrict__ outT, int K, int N,
    int scale_cols, float scale) {
  __shared__ float tile[32][33];
  const int tx = threadIdx.x & 31;
  const int ty = threadIdx.x >> 5;  // 0..7
  const int n0 = blockIdx.x * 32;
  const int k0 = blockIdx.y * 32;
#pragma unroll
  for (int j = 0; j < 4; ++j)
    tile[ty + j * 8][tx] = in[(size_t)(k0 + ty + j * 8) * N + n0 + tx];
  __syncthreads();
#pragma unroll
  for (int j = 0; j < 4; ++j) {
    int n = n0 + ty + j * 8;
    float s = (n < scale_cols) ? scale : 1.0f;
    outT[(size_t)n * K + k0 + tx] = (bf16_t)(tile[tx][ty + j * 8] * s);
  }
}

// ---------------------------------------------------------------------------
// GEMM (m97 structure): C[M,N] = A[M,K] @ Bt[N,K]^T. bf16 in, OutT out.
// ---------------------------------------------------------------------------
template <typename OutT>
__global__ __launch_bounds__(256) void gemm_bt_kernel(
    const bf16_t* __restrict__ A, const bf16_t* __restrict__ Bt,
    OutT* __restrict__ C, int M, int N, int K) {
  __shared__ __align__(16) bf16_t As[128 * 64];
  __shared__ __align__(16) bf16_t Bs[128 * 64];

  const int tid = threadIdx.x;
  const int lane = tid & 63;
  const int wid = tid >> 6;
  const int l16 = lane & 15;
  const int g4 = lane >> 4;
  const int m0 = blockIdx.y * 128;
  const int n0 = blockIdx.x * 128;
  const int wm = (wid >> 1) * 64;
  const int wn = (wid & 1) * 64;

  const int srow = wid * 8 + (lane >> 3);
  const int scol = (lane & 7) * 8;
  const bf16_t* ap = A + (size_t)(m0 + srow) * K + scol;
  const bf16_t* bp = Bt + (size_t)(n0 + srow) * K + scol;

  f32x4 acc[4][4] = {};

  for (int k0 = 0; k0 < K; k0 += 64) {
    __syncthreads();
#pragma unroll
    for (int t = 0; t < 4; ++t) {
      gload_lds16(ap + k0 + (size_t)t * 32 * K, &As[(t * 32 + wid * 8) * 64]);
      gload_lds16(bp + k0 + (size_t)t * 32 * K, &Bs[(t * 32 + wid * 8) * 64]);
    }
    __syncthreads();

#pragma unroll
    for (int ks = 0; ks < 2; ++ks) {
      bf16x8 af[4], bfm[4];
#pragma unroll
      for (int i = 0; i < 4; ++i)
        af[i] = *reinterpret_cast<const bf16x8*>(
            &As[(wm + i * 16 + l16) * 64 + ks * 32 + g4 * 8]);
#pragma unroll
      for (int i = 0; i < 4; ++i)
        bfm[i] = *reinterpret_cast<const bf16x8*>(
            &Bs[(wn + i * 16 + l16) * 64 + ks * 32 + g4 * 8]);
#pragma unroll
      for (int mi = 0; mi < 4; ++mi)
#pragma unroll
        for (int ni = 0; ni < 4; ++ni)
          acc[mi][ni] = __builtin_amdgcn_mfma_f32_16x16x32_bf16(
              af[mi], bfm[ni], acc[mi][ni], 0, 0, 0);
    }
  }

#pragma unroll
  for (int mi = 0; mi < 4; ++mi)
#pragma unroll
    for (int ni = 0; ni < 4; ++ni)
#pragma unroll
      for (int r = 0; r < 4; ++r) {
        int row = m0 + wm + mi * 16 + g4 * 4 + r;
        int col = n0 + wn + ni * 16 + l16;
        C[(size_t)row * N + col] = (OutT)acc[mi][ni][r];
      }
}

// ---------------------------------------------------------------------------
// Flash attention body: one 128-key step, fully prefetched pipeline.
//   [issue K(i+1) -> kf_load][stage V(i+1) -> other buf]
//   [vmcnt(8): K(i) regs + V(i) LDS ready (issued one body earlier)]
//   [tr_read V(i)][QK with kf_use][exp2][lgkm(0)][PV + lsum-MFMA]
// Q pre-scaled by 0.125*log2(e) in w_qkv -> exp2 directly.
// ---------------------------------------------------------------------------
__device__ __forceinline__ void attn_body(
    const bf16_t* kp_next, const bf16_t* vp_next, bf16_t* vst_next,
    unsigned vrd_cur, uint32x4 (&kf_use)[2][2], uint32x4 (&kf_load)[2][2],
    const bf16x8 (&qf)[4][2], const bf16x8 vones, f32x4 (&acc_o)[16],
    f32x4 (&acc_l)[4]) {
  // ---- issue K(i+1) loads (land in kf_load; consumed NEXT body)
#pragma unroll
  for (int half = 0; half < 2; ++half)
#pragma unroll
    for (int kh = 0; kh < 2; ++kh)
      asm volatile("global_load_dwordx4 %0, %1, off"
                   : "=v"(kf_load[half][kh])
                   : "v"(kp_next + (size_t)half * 64 * RSQ + kh * 32)
                   : "memory");

  // ---- stage V(i+1) (wave-private, async)
#pragma unroll
  for (int t = 0; t < 4; ++t)
    gload_lds16(vp_next + t * 16, vst_next + t * 512);

  // ---- single wait: everything older than this body's 8 issues is done
  asm volatile("s_waitcnt vmcnt(8)" ::: "memory");
  __builtin_amdgcn_sched_barrier(0);

  // ---- V(i) B-frags via HW transpose read (per-lane addr = base + lane*8)
  uint32x2 vr[4][2];
#define TRR(dst, OFFSTR)                              \
  asm volatile("ds_read_b64_tr_b16 %0, %1 offset:" OFFSTR \
               : "=v"(dst)                            \
               : "v"(vrd_cur))
  TRR(vr[0][0], "0");    TRR(vr[0][1], "512");
  TRR(vr[1][0], "1024"); TRR(vr[1][1], "1536");
  TRR(vr[2][0], "2048"); TRR(vr[2][1], "2560");
  TRR(vr[3][0], "3072"); TRR(vr[3][1], "3584");
#undef TRR

  // ---- swapped QK^T: s[key][q] (Q pre-scaled); kf_use ready per vmcnt(8)
  f32x4 sA[4] = {}, sB[4] = {};
#pragma unroll
  for (int qb = 0; qb < 4; ++qb) {
    sA[qb] = __builtin_amdgcn_mfma_f32_16x16x32_bf16(
        __builtin_bit_cast(bf16x8, kf_use[0][0]), qf[qb][0], sA[qb], 0, 0, 0);
    sA[qb] = __builtin_amdgcn_mfma_f32_16x16x32_bf16(
        __builtin_bit_cast(bf16x8, kf_use[0][1]), qf[qb][1], sA[qb], 0, 0, 0);
    sB[qb] = __builtin_amdgcn_mfma_f32_16x16x32_bf16(
        __builtin_bit_cast(bf16x8, kf_use[1][0]), qf[qb][0], sB[qb], 0, 0, 0);
    sB[qb] = __builtin_amdgcn_mfma_f32_16x16x32_bf16(
        __builtin_bit_cast(bf16x8, kf_use[1][1]), qf[qb][1], sB[qb], 0, 0, 0);
  }

  // ---- exp2 + pack to PV A-frags (keys lane-local; lsum via MFMA below)
  bf16x8 pf[4];
#pragma unroll
  for (int qb = 0; qb < 4; ++qb) {
    pf[qb][0] = (bf16_t)__builtin_amdgcn_exp2f(sA[qb][0]);
    pf[qb][1] = (bf16_t)__builtin_amdgcn_exp2f(sA[qb][1]);
    pf[qb][2] = (bf16_t)__builtin_amdgcn_exp2f(sA[qb][2]);
    pf[qb][3] = (bf16_t)__builtin_amdgcn_exp2f(sA[qb][3]);
    pf[qb][4] = (bf16_t)__builtin_amdgcn_exp2f(sB[qb][0]);
    pf[qb][5] = (bf16_t)__builtin_amdgcn_exp2f(sB[qb][1]);
    pf[qb][6] = (bf16_t)__builtin_amdgcn_exp2f(sB[qb][2]);
    pf[qb][7] = (bf16_t)__builtin_amdgcn_exp2f(sB[qb][3]);
  }

  // ---- tr_reads complete; build vf; lsum-MFMA + PV
  asm volatile("s_waitcnt lgkmcnt(0)" ::: "memory");
  __builtin_amdgcn_sched_barrier(0);
  bf16x8 vf[4];
#pragma unroll
  for (int db = 0; db < 4; ++db) {
    uint32x4 c = {vr[db][0].x, vr[db][0].y, vr[db][1].x, vr[db][1].y};
    vf[db] = __builtin_bit_cast(bf16x8, c);
  }
#pragma unroll
  for (int qb = 0; qb < 4; ++qb) {
    acc_l[qb] = __builtin_amdgcn_mfma_f32_16x16x32_bf16(
        pf[qb], vones, acc_l[qb], 0, 0, 0);
#pragma unroll
    for (int db = 0; db < 4; ++db)
      acc_o[qb * 4 + db] = __builtin_amdgcn_mfma_f32_16x16x32_bf16(
          pf[qb], vf[db], acc_o[qb * 4 + db], 0, 0, 0);
  }
}

// ---------------------------------------------------------------------------
__global__ __launch_bounds__(256) void attn_kernel(
    const bf16_t* __restrict__ qkv, bf16_t* __restrict__ out) {
  __shared__ __align__(16) unsigned char smem[33792];
  bf16_t* Vlds = (bf16_t*)smem;            // [4 waves][2 bufs][2048] = 32 KiB
  float(*Obuf)[66] = (float(*)[66])smem;   // aliases Vlds (k-loop finished)
  float* lbuf = (float*)(smem + 32768);    // [4][64] floats

  const int tid = threadIdx.x;
  const int lane = tid & 63;
  const int wid = tid >> 6;
  const int l16 = lane & 15;
  const int g4 = lane >> 4;

  // XCD-aware decode: all 32 q-tiles of one (b,h) on one XCD
  const int D = blockIdx.x;
  const int g = ((D >> 8) << 3) + (D & 7);
  const int h = g & 15;
  const int b = g >> 4;
  const int q0 = ((D >> 3) & 31) * 64;

  const size_t base = (size_t)b * SEQ * RSQ;

  // ---- Q fragments (pre-scaled by 0.125*log2e via w_qkv), hoisted
  bf16x8 qf[4][2];
#pragma unroll
  for (int qb = 0; qb < 4; ++qb)
#pragma unroll
    for (int kh = 0; kh < 2; ++kh)
      qf[qb][kh] = __builtin_bit_cast(
          bf16x8, *reinterpret_cast<const uint4*>(
                      qkv + base + (size_t)(q0 + qb * 16 + l16) * RSQ + h * DH +
                      kh * 32 + g4 * 8));

  const bf16_t* kbase =
      qkv + base + (size_t)(wid * 16 + l16) * RSQ + DM + h * DH + g4 * 8;

  // V staging source (pre-swizzled: linear LDS == [db][eh][g4][j][l16])
  const int keyoff = ((lane >> 5) << 6) + wid * 16 + (((lane >> 3) & 3) << 2) +
                     ((lane >> 1) & 3);
  const bf16_t* vsrc =
      qkv + base + (size_t)keyoff * RSQ + 2 * DM + h * DH + (lane & 1) * 8;
  bf16_t* vwave = Vlds + wid * 4096;  // 2 buffers of 2048
  const unsigned vlane = lds_b32addr(vwave) + (lane << 3);

  bf16x8 vones;
#pragma unroll
  for (int e = 0; e < 8; ++e) vones[e] = (bf16_t)1.0f;

  f32x4 acc_o[16] = {};
  f32x4 acc_l[4] = {};
  uint32x4 kfA[2][2], kfB[2][2];

  // ---- prologue: issue K(0) into kfA; stage V(0) into buffer 0
#pragma unroll
  for (int half = 0; half < 2; ++half)
#pragma unroll
    for (int kh = 0; kh < 2; ++kh)
      asm volatile("global_load_dwordx4 %0, %1, off"
                   : "=v"(kfA[half][kh])
                   : "v"(kbase + (size_t)half * 64 * RSQ + kh * 32)
                   : "memory");
#pragma unroll
  for (int t = 0; t < 4; ++t) gload_lds16(vsrc + t * 16, vwave + t * 512);

  // ---- pipelined k-loop (2-body unroll, kfA/kfB ping-pong, wrap prefetch)
  for (int i = 0; i < 16; i += 2) {
    const int i1 = (i + 1) & 15;
    const int i2 = (i + 2) & 15;
    attn_body(kbase + (size_t)i1 * 128 * RSQ, vsrc + (size_t)i1 * 128 * RSQ,
              vwave + 2048, vlane, kfA, kfB, qf, vones, acc_o, acc_l);
    attn_body(kbase + (size_t)i2 * 128 * RSQ, vsrc + (size_t)i2 * 128 * RSQ,
              vwave, vlane + 4096, kfB, kfA, qf, vones, acc_o, acc_l);
  }
  // drain: last body's dummy prefetch must land before Obuf overwrites Vlds
  asm volatile("s_waitcnt vmcnt(0)" ::: "memory");

  // ---- per-wave l partials (acc_l[qb][r] = l for q=qb*16+g4*4+r, any col)
  if (l16 == 0) {
#pragma unroll
    for (int qb = 0; qb < 4; ++qb)
#pragma unroll
      for (int r = 0; r < 4; ++r)
        lbuf[wid * 64 + qb * 16 + g4 * 4 + r] = acc_l[qb][r];
  }

  // ---- cross-wave O reduction (Obuf aliases Vlds; safe after first barrier)
  for (int ph = 0; ph < 4; ++ph) {
    __syncthreads();
    if (wid == ph) {
#pragma unroll
      for (int qb = 0; qb < 4; ++qb)
#pragma unroll
        for (int db = 0; db < 4; ++db)
#pragma unroll
          for (int r = 0; r < 4; ++r) {
            int q = qb * 16 + g4 * 4 + r;
            int d = db * 16 + l16;
            if (ph == 0)
              Obuf[q][d] = acc_o[qb * 4 + db][r];
            else
              Obuf[q][d] += acc_o[qb * 4 + db][r];
          }
    }
  }
  __syncthreads();

  // ---- epilogue
  {
    int q = wid * 16 + l16;
    float l = lbuf[0 * 64 + q] + lbuf[1 * 64 + q] + lbuf[2 * 64 + q] +
              lbuf[3 * 64 + q];
    float inv = 1.f / l;
    bf16_t ob[16];
#pragma unroll
    for (int c = 0; c < 16; ++c)
      ob[c] = (bf16_t)(Obuf[q][g4 * 16 + c] * inv);
    bf16_t* op = out + (size_t)(b * SEQ + q0 + q) * DM + h * DH + g4 * 16;
    *reinterpret_cast<uint4*>(op) = *reinterpret_cast<const uint4*>(&ob[0]);
    *reinterpret_cast<uint4*>(op + 8) = *reinterpret_cast<const uint4*>(&ob[8]);
  }
}

// ---------------------------------------------------------------------------
extern "C" void kernel_launch(void* const* d_in, const int* in_sizes, int n_in,
                              void* d_out, int out_size, void* d_ws, size_t ws_size,
                              hipStream_t stream) {
  const float* x = (const float*)d_in[0];       // [4,2048,1024] fp32
  const float* w_qkv = (const float*)d_in[1];   // [1024,3072] fp32
  const float* w_o = (const float*)d_in[2];     // [1024,1024] fp32
  float* out = (float*)d_out;                   // [4,2048,1024] fp32

  bf16_t* xb = (bf16_t*)d_ws;                        // [8192][1024]
  bf16_t* wqkvt = xb + (size_t)8192 * 1024;          // [3072][1024]
  bf16_t* wot = wqkvt + (size_t)3072 * 1024;         // [1024][1024]
  bf16_t* qkv = wot + (size_t)1024 * 1024;           // [8192][3072]
  bf16_t* attn = qkv + (size_t)8192 * 3072;          // [8192][1024]

  dim3 blk(256);
  const float c_exp2 = 0.18033688011112042f;  // 0.125 * log2(e)

  f32_to_bf16_kernel<<<8192, blk, 0, stream>>>(x, xb, 8192 * 1024);
  // q-columns (output rows [0,1024)) pre-scaled -> attn uses exp2 directly
  transpose_f32_bf16_kernel<<<dim3(3072 / 32, 1024 / 32), blk, 0, stream>>>(
      w_qkv, wqkvt, 1024, 3072, 1024, c_exp2);
  transpose_f32_bf16_kernel<<<dim3(1024 / 32, 1024 / 32), blk, 0, stream>>>(
      w_o, wot, 1024, 1024, 0, 1.0f);

  gemm_bt_kernel<bf16_t><<<dim3(3072 / 128, 8192 / 128), blk, 0, stream>>>(
      xb, wqkvt, qkv, 8192, 3072, 1024);
  attn_kernel<<<2048, blk, 0, stream>>>(qkv, attn);
  gemm_bt_kernel<float><<<dim3(1024 / 128, 8192 / 128), blk, 0, stream>>>(
      attn, wot, out, 8192, 1024, 1024);
}

// Round 8
// 233.462 us; speedup vs baseline: 1.0768x; 1.0768x over previous
//
#include <hip/hip_runtime.h>
#include <hip/hip_bf16.h>

typedef __bf16 bf16_t;
typedef __bf16 bf16x8 __attribute__((ext_vector_type(8)));
typedef float f32x4 __attribute__((ext_vector_type(4)));
typedef unsigned int uint32x2 __attribute__((ext_vector_type(2)));
typedef unsigned int uint32x4 __attribute__((ext_vector_type(4)));

#define B_SZ 4
#define SEQ 2048
#define NH 16
#define DH 64
#define DM 1024
#define RSQ (3 * DM)

// async global->LDS, 16B per lane. LDS dest = wave-uniform base + lane*16.
__device__ __forceinline__ void gload_lds16(const bf16_t* g, bf16_t* l) {
  __builtin_amdgcn_global_load_lds(
      (const __attribute__((address_space(1))) unsigned int*)g,
      (__attribute__((address_space(3))) unsigned int*)l, 16, 0, 0);
}

__device__ __forceinline__ unsigned lds_b32addr(void* p) {
  return (unsigned)(uintptr_t)(__attribute__((address_space(3))) void*)p;
}

// ---------------------------------------------------------------------------
// fp32 -> bf16 elementwise convert, 4 elems/thread.
// ---------------------------------------------------------------------------
__global__ __launch_bounds__(256) void f32_to_bf16_kernel(
    const float* __restrict__ in, bf16_t* __restrict__ out, int n) {
  int i = (blockIdx.x * blockDim.x + threadIdx.x) * 4;
  if (i >= n) return;
  float4 v = *reinterpret_cast<const float4*>(in + i);
  bf16_t o[4] = {(bf16_t)v.x, (bf16_t)v.y, (bf16_t)v.z, (bf16_t)v.w};
  *reinterpret_cast<uint2*>(out + i) = *reinterpret_cast<const uint2*>(o);
}

// ---------------------------------------------------------------------------
// fp32 [K][N] -> bf16 transposed [N][K], output rows < scale_cols scaled.
// ---------------------------------------------------------------------------
__global__ __launch_bounds__(256) void transpose_f32_bf16_kernel(
    const float* __restrict__ in, bf16_t* __restrict__ outT, int K, int N,
    int scale_cols, float scale) {
  __shared__ float tile[32][33];
  const int tx = threadIdx.x & 31;
  const int ty = threadIdx.x >> 5;  // 0..7
  const int n0 = blockIdx.x * 32;
  const int k0 = blockIdx.y * 32;
#pragma unroll
  for (int j = 0; j < 4; ++j)
    tile[ty + j * 8][tx] = in[(size_t)(k0 + ty + j * 8) * N + n0 + tx];
  __syncthreads();
#pragma unroll
  for (int j = 0; j < 4; ++j) {
    int n = n0 + ty + j * 8;
    float s = (n < scale_cols) ? scale : 1.0f;
    outT[(size_t)n * K + k0 + tx] = (bf16_t)(tile[tx][ty + j * 8] * s);
  }
}

// ---------------------------------------------------------------------------
// 8-phase-style GEMM: C[M,N] = A[M,K] @ Bt[N,K]^T. bf16 in, OutT out.
// BM=128, BN=256, BK=64. 512 threads = 8 waves (2M x 4N), per-wave 64x64.
// Double-buffered LDS (96 KiB), raw s_barrier + counted vmcnt (loads stay in
// flight across barriers), 2 phases per K-tile x 16 MFMA, setprio on MFMA.
// Grid: (M/128)*(N/256) blocks; both GEMM shapes give multiples of 256 blocks.
// ---------------------------------------------------------------------------
template <typename OutT>
__global__ __launch_bounds__(512, 2) void gemm8p_kernel(
    const bf16_t* __restrict__ A, const bf16_t* __restrict__ Bt,
    OutT* __restrict__ C, int M, int N, int K, int NB) {
  __shared__ __align__(16) bf16_t As[2][128 * 64];  // 32 KiB
  __shared__ __align__(16) bf16_t Bs[2][256 * 64];  // 64 KiB

  const int tid = threadIdx.x;
  const int lane = tid & 63;
  const int wid = tid >> 6;  // 0..7
  const int l16 = lane & 15;
  const int g4 = lane >> 4;
  const int wm = wid >> 2;   // 0..1
  const int wn = wid & 3;    // 0..3
  const int tiles = K >> 6;  // K-tiles of 64

  // XCD swizzle (nwg % 8 == 0 for both shapes)
  const int nwg = gridDim.x;
  const int bid = blockIdx.x;
  const int swz = (bid & 7) * (nwg >> 3) + (bid >> 3);
  const int m0 = (swz / NB) * 128;
  const int n0 = (swz % NB) * 256;

  // ---- staging maps ----
  // A: inst i covers rows [m0 + i*64 + (tid>>3)], col (tid&7)*8.
  //    dest elem = i*4096 + tid*8 (linear; per-wave base i*4096 + wid*512).
  const bf16_t* aglob = A + (size_t)(m0 + (tid >> 3)) * K + (tid & 7) * 8;
  // B half h (h=0 -> each wave's Nfrag {0,1} rows, h=1 -> {2,3}):
  //    inst j, wave w: wrow = (2j + (w>>2))*64 + (w&3)*8 + h*32
  //    lane l covers row wrow + (l>>3), col (l&7)*8; dest = wrow*64 + l*8.

  auto stageA = [&](int t) {
    int tt = (t == tiles) ? 0 : t;
    int k0 = tt * 64;
    int buf = tt & 1;
#pragma unroll
    for (int i = 0; i < 2; ++i)
      gload_lds16(aglob + (size_t)i * 64 * K + k0,
                  &As[buf][i * 4096 + wid * 512]);
  };
  auto stageB = [&](int t, int h) {
    int tt = (t == tiles) ? 0 : t;
    int k0 = tt * 64;
    int buf = tt & 1;
#pragma unroll
    for (int j = 0; j < 2; ++j) {
      int wrow = (2 * j + (wid >> 2)) * 64 + (wid & 3) * 8 + h * 32;
      gload_lds16(
          Bt + (size_t)(n0 + wrow + (lane >> 3)) * K + k0 + (lane & 7) * 8,
          &Bs[buf][wrow * 64]);
    }
  };

  f32x4 acc[4][4] = {};

  // ---- prologue: A(0)+Bh0(0) (4 loads), Bh1(0) (2 loads); wait first 4.
  stageA(0);
  stageB(0, 0);
  stageB(0, 1);
  asm volatile("s_waitcnt vmcnt(2)" ::: "memory");
  __builtin_amdgcn_s_barrier();
  __builtin_amdgcn_sched_barrier(0);

#pragma unroll 2
  for (int t = 0; t < tiles; ++t) {
    const int buf = t & 1;
    const int abase = (wm * 64 + l16) * 64 + g4 * 8;
    const int bbase = (wn * 64 + l16) * 64 + g4 * 8;

    // ======== phase 1: quadrants n={0,1} ========
    bf16x8 af[4][2], bf[2][2];
#pragma unroll
    for (int m = 0; m < 4; ++m)
#pragma unroll
      for (int ks = 0; ks < 2; ++ks)
        af[m][ks] = *reinterpret_cast<const bf16x8*>(
            &As[buf][abase + m * 16 * 64 + ks * 32]);
#pragma unroll
    for (int n = 0; n < 2; ++n)
#pragma unroll
      for (int ks = 0; ks < 2; ++ks)
        bf[n][ks] = *reinterpret_cast<const bf16x8*>(
            &Bs[buf][bbase + n * 16 * 64 + ks * 32]);

    stageA(t + 1);
    stageB(t + 1, 0);
    // Bh1(t) must be landed before phase 2 reads; leave this phase's 4 loads.
    asm volatile("s_waitcnt vmcnt(4)" ::: "memory");
    __builtin_amdgcn_s_barrier();
    __builtin_amdgcn_sched_barrier(0);

    __builtin_amdgcn_s_setprio(1);
#pragma unroll
    for (int m = 0; m < 4; ++m)
#pragma unroll
      for (int n = 0; n < 2; ++n)
#pragma unroll
        for (int ks = 0; ks < 2; ++ks)
          acc[m][n] = __builtin_amdgcn_mfma_f32_16x16x32_bf16(
              af[m][ks], bf[n][ks], acc[m][n], 0, 0, 0);
    __builtin_amdgcn_s_setprio(0);
    __builtin_amdgcn_s_barrier();
    __builtin_amdgcn_sched_barrier(0);

    // ======== phase 2: quadrants n={2,3} ========
    bf16x8 bg[2][2];
#pragma unroll
    for (int n = 0; n < 2; ++n)
#pragma unroll
      for (int ks = 0; ks < 2; ++ks)
        bg[n][ks] = *reinterpret_cast<const bf16x8*>(
            &Bs[buf][bbase + (n + 2) * 16 * 64 + ks * 32]);

    stageB(t + 1, 1);
    // A(t+1)+Bh0(t+1) must be landed before next phase-1 reads.
    asm volatile("s_waitcnt vmcnt(2)" ::: "memory");
    __builtin_amdgcn_s_barrier();
    __builtin_amdgcn_sched_barrier(0);

    __builtin_amdgcn_s_setprio(1);
#pragma unroll
    for (int m = 0; m < 4; ++m)
#pragma unroll
      for (int n = 0; n < 2; ++n)
#pragma unroll
        for (int ks = 0; ks < 2; ++ks)
          acc[m][n + 2] = __builtin_amdgcn_mfma_f32_16x16x32_bf16(
              af[m][ks], bg[n][ks], acc[m][n + 2], 0, 0, 0);
    __builtin_amdgcn_s_setprio(0);
    __builtin_amdgcn_s_barrier();
    __builtin_amdgcn_sched_barrier(0);
  }

  // drain wrap-around dummy stages before exit
  asm volatile("s_waitcnt vmcnt(0)" ::: "memory");

  // ---- epilogue: C/D layout col=l16, row=g4*4+r
#pragma unroll
  for (int m = 0; m < 4; ++m)
#pragma unroll
    for (int n = 0; n < 4; ++n)
#pragma unroll
      for (int r = 0; r < 4; ++r) {
        int row = m0 + wm * 64 + m * 16 + g4 * 4 + r;
        int col = n0 + wn * 64 + n * 16 + l16;
        C[(size_t)row * N + col] = (OutT)acc[m][n][r];
      }
}

// ---------------------------------------------------------------------------
// Flash attention body (round-6 version): one 128-key step.
//   [asm K(i) loads][stage V(i+1) -> other buf][vmcnt(8): V(i) landed]
//   [tr_read V(i)][vmcnt(4): K(i) ready, V(i+1) in flight][QK][exp][PV]
// Q pre-scaled by 0.125*log2(e) in w_qkv -> exp2 directly.
// ---------------------------------------------------------------------------
template <bool PRE>
__device__ __forceinline__ void attn_body(
    const bf16_t* kp, const bf16_t* vp_next, bf16_t* vst_next, unsigned vrd,
    const bf16x8 (&qf)[4][2], f32x4 (&acc_o)[16], float (&lsum)[4]) {
  uint32x4 kf[2][2];
#pragma unroll
  for (int half = 0; half < 2; ++half)
#pragma unroll
    for (int kh = 0; kh < 2; ++kh)
      asm volatile("global_load_dwordx4 %0, %1, off"
                   : "=v"(kf[half][kh])
                   : "v"(kp + (size_t)half * 64 * RSQ + kh * 32)
                   : "memory");

  if constexpr (PRE) {
#pragma unroll
    for (int t = 0; t < 4; ++t)
      gload_lds16(vp_next + t * 16, vst_next + t * 512);
  }

  if constexpr (PRE)
    asm volatile("s_waitcnt vmcnt(8)" ::: "memory");
  else
    asm volatile("s_waitcnt vmcnt(4)" ::: "memory");

  uint32x2 vr[4][2];
#define TRR(dst, OFFSTR)                              \
  asm volatile("ds_read_b64_tr_b16 %0, %1 offset:" OFFSTR \
               : "=v"(dst)                            \
               : "v"(vrd))
  TRR(vr[0][0], "0");    TRR(vr[0][1], "512");
  TRR(vr[1][0], "1024"); TRR(vr[1][1], "1536");
  TRR(vr[2][0], "2048"); TRR(vr[2][1], "2560");
  TRR(vr[3][0], "3072"); TRR(vr[3][1], "3584");
#undef TRR

  if constexpr (PRE)
    asm volatile("s_waitcnt vmcnt(4)" ::: "memory");
  else
    asm volatile("s_waitcnt vmcnt(0)" ::: "memory");
  __builtin_amdgcn_sched_barrier(0);  // rule 18

  f32x4 sA[4] = {}, sB[4] = {};
#pragma unroll
  for (int qb = 0; qb < 4; ++qb) {
    sA[qb] = __builtin_amdgcn_mfma_f32_16x16x32_bf16(
        __builtin_bit_cast(bf16x8, kf[0][0]), qf[qb][0], sA[qb], 0, 0, 0);
    sA[qb] = __builtin_amdgcn_mfma_f32_16x16x32_bf16(
        __builtin_bit_cast(bf16x8, kf[0][1]), qf[qb][1], sA[qb], 0, 0, 0);
    sB[qb] = __builtin_amdgcn_mfma_f32_16x16x32_bf16(
        __builtin_bit_cast(bf16x8, kf[1][0]), qf[qb][0], sB[qb], 0, 0, 0);
    sB[qb] = __builtin_amdgcn_mfma_f32_16x16x32_bf16(
        __builtin_bit_cast(bf16x8, kf[1][1]), qf[qb][1], sB[qb], 0, 0, 0);
  }

  bf16x8 pf[4];
#pragma unroll
  for (int qb = 0; qb < 4; ++qb) {
    float p0 = __builtin_amdgcn_exp2f(sA[qb][0]);
    float p1 = __builtin_amdgcn_exp2f(sA[qb][1]);
    float p2 = __builtin_amdgcn_exp2f(sA[qb][2]);
    float p3 = __builtin_amdgcn_exp2f(sA[qb][3]);
    float p4 = __builtin_amdgcn_exp2f(sB[qb][0]);
    float p5 = __builtin_amdgcn_exp2f(sB[qb][1]);
    float p6 = __builtin_amdgcn_exp2f(sB[qb][2]);
    float p7 = __builtin_amdgcn_exp2f(sB[qb][3]);
    lsum[qb] += ((p0 + p1) + (p2 + p3)) + ((p4 + p5) + (p6 + p7));
    pf[qb][0] = (bf16_t)p0; pf[qb][1] = (bf16_t)p1;
    pf[qb][2] = (bf16_t)p2; pf[qb][3] = (bf16_t)p3;
    pf[qb][4] = (bf16_t)p4; pf[qb][5] = (bf16_t)p5;
    pf[qb][6] = (bf16_t)p6; pf[qb][7] = (bf16_t)p7;
  }

  asm volatile("s_waitcnt lgkmcnt(0)" ::: "memory");
  __builtin_amdgcn_sched_barrier(0);
  bf16x8 vf[4];
#pragma unroll
  for (int db = 0; db < 4; ++db) {
    uint32x4 c = {vr[db][0].x, vr[db][0].y, vr[db][1].x, vr[db][1].y};
    vf[db] = __builtin_bit_cast(bf16x8, c);
  }
#pragma unroll
  for (int qb = 0; qb < 4; ++qb)
#pragma unroll
    for (int db = 0; db < 4; ++db)
      acc_o[qb * 4 + db] = __builtin_amdgcn_mfma_f32_16x16x32_bf16(
          pf[qb], vf[db], acc_o[qb * 4 + db], 0, 0, 0);
}

// ---------------------------------------------------------------------------
__global__ __launch_bounds__(256) void attn_kernel(
    const bf16_t* __restrict__ qkv, bf16_t* __restrict__ out) {
  __shared__ __align__(16) unsigned char smem[33792];
  bf16_t* Vlds = (bf16_t*)smem;            // [4 waves][2 bufs][2048] = 32 KiB
  float(*Obuf)[66] = (float(*)[66])smem;   // aliases Vlds (k-loop finished)
  float* lbuf = (float*)(smem + 32768);    // [4][64] floats

  const int tid = threadIdx.x;
  const int lane = tid & 63;
  const int wid = tid >> 6;
  const int l16 = lane & 15;
  const int g4 = lane >> 4;

  const int D = blockIdx.x;
  const int g = ((D >> 8) << 3) + (D & 7);
  const int h = g & 15;
  const int b = g >> 4;
  const int q0 = ((D >> 3) & 31) * 64;

  const size_t base = (size_t)b * SEQ * RSQ;

  bf16x8 qf[4][2];
#pragma unroll
  for (int qb = 0; qb < 4; ++qb)
#pragma unroll
    for (int kh = 0; kh < 2; ++kh)
      qf[qb][kh] = __builtin_bit_cast(
          bf16x8, *reinterpret_cast<const uint4*>(
                      qkv + base + (size_t)(q0 + qb * 16 + l16) * RSQ + h * DH +
                      kh * 32 + g4 * 8));

  const bf16_t* kbase =
      qkv + base + (size_t)(wid * 16 + l16) * RSQ + DM + h * DH + g4 * 8;

  const int keyoff = ((lane >> 5) << 6) + wid * 16 + (((lane >> 3) & 3) << 2) +
                     ((lane >> 1) & 3);
  const bf16_t* vsrc =
      qkv + base + (size_t)keyoff * RSQ + 2 * DM + h * DH + (lane & 1) * 8;
  bf16_t* vwave = Vlds + wid * 4096;  // 2 buffers of 2048
  const unsigned vlane = lds_b32addr(vwave) + (lane << 3);

  f32x4 acc_o[16] = {};
  float lsum[4] = {0.f, 0.f, 0.f, 0.f};

#pragma unroll
  for (int t = 0; t < 4; ++t) gload_lds16(vsrc + t * 16, vwave + t * 512);

  for (int i = 0; i < 15; ++i) {
    const bf16_t* kp = kbase + (size_t)i * 128 * RSQ;
    const bf16_t* vp_next = vsrc + (size_t)(i + 1) * 128 * RSQ;
    bf16_t* vst_next = vwave + ((i + 1) & 1) * 2048;
    unsigned vrd = vlane + (i & 1) * 4096;
    attn_body<true>(kp, vp_next, vst_next, vrd, qf, acc_o, lsum);
  }
  attn_body<false>(kbase + (size_t)15 * 128 * RSQ, nullptr, nullptr,
                   vlane + 4096, qf, acc_o, lsum);

#pragma unroll
  for (int qb = 0; qb < 4; ++qb) {
    float t = lsum[qb];
    t += __shfl_xor(t, 16, 64);
    t += __shfl_xor(t, 32, 64);
    if (g4 == 0) lbuf[wid * 64 + qb * 16 + l16] = t;
  }

  for (int ph = 0; ph < 4; ++ph) {
    __syncthreads();
    if (wid == ph) {
#pragma unroll
      for (int qb = 0; qb < 4; ++qb)
#pragma unroll
        for (int db = 0; db < 4; ++db)
#pragma unroll
          for (int r = 0; r < 4; ++r) {
            int q = qb * 16 + g4 * 4 + r;
            int d = db * 16 + l16;
            if (ph == 0)
              Obuf[q][d] = acc_o[qb * 4 + db][r];
            else
              Obuf[q][d] += acc_o[qb * 4 + db][r];
          }
    }
  }
  __syncthreads();

  {
    int q = wid * 16 + l16;
    float l = lbuf[0 * 64 + q] + lbuf[1 * 64 + q] + lbuf[2 * 64 + q] +
              lbuf[3 * 64 + q];
    float inv = 1.f / l;
    bf16_t ob[16];
#pragma unroll
    for (int c = 0; c < 16; ++c)
      ob[c] = (bf16_t)(Obuf[q][g4 * 16 + c] * inv);
    bf16_t* op = out + (size_t)(b * SEQ + q0 + q) * DM + h * DH + g4 * 16;
    *reinterpret_cast<uint4*>(op) = *reinterpret_cast<const uint4*>(&ob[0]);
    *reinterpret_cast<uint4*>(op + 8) = *reinterpret_cast<const uint4*>(&ob[8]);
  }
}

// ---------------------------------------------------------------------------
extern "C" void kernel_launch(void* const* d_in, const int* in_sizes, int n_in,
                              void* d_out, int out_size, void* d_ws, size_t ws_size,
                              hipStream_t stream) {
  const float* x = (const float*)d_in[0];       // [4,2048,1024] fp32
  const float* w_qkv = (const float*)d_in[1];   // [1024,3072] fp32
  const float* w_o = (const float*)d_in[2];     // [1024,1024] fp32
  float* out = (float*)d_out;                   // [4,2048,1024] fp32

  bf16_t* xb = (bf16_t*)d_ws;                        // [8192][1024]
  bf16_t* wqkvt = xb + (size_t)8192 * 1024;          // [3072][1024]
  bf16_t* wot = wqkvt + (size_t)3072 * 1024;         // [1024][1024]
  bf16_t* qkv = wot + (size_t)1024 * 1024;           // [8192][3072]
  bf16_t* attn = qkv + (size_t)8192 * 3072;          // [8192][1024]

  const float c_exp2 = 0.18033688011112042f;  // 0.125 * log2(e)

  f32_to_bf16_kernel<<<8192, 256, 0, stream>>>(x, xb, 8192 * 1024);
  transpose_f32_bf16_kernel<<<dim3(3072 / 32, 1024 / 32), 256, 0, stream>>>(
      w_qkv, wqkvt, 1024, 3072, 1024, c_exp2);
  transpose_f32_bf16_kernel<<<dim3(1024 / 32, 1024 / 32), 256, 0, stream>>>(
      w_o, wot, 1024, 1024, 0, 1.0f);

  // qkv = x @ w_qkv : 64x12 = 768 blocks (3 exact CU rounds)
  gemm8p_kernel<bf16_t><<<768, 512, 0, stream>>>(
      xb, wqkvt, qkv, 8192, 3072, 1024, 12);
  attn_kernel<<<2048, 256, 0, stream>>>(qkv, attn);
  // out = attn @ w_o : 64x4 = 256 blocks (1 exact CU round)
  gemm8p_kernel<float><<<256, 512, 0, stream>>>(
      attn, wot, out, 8192, 1024, 1024, 4);
}

// Round 9
// 223.500 us; speedup vs baseline: 1.1248x; 1.0446x over previous
//
#include <hip/hip_runtime.h>
#include <hip/hip_bf16.h>

typedef __bf16 bf16_t;
typedef __bf16 bf16x8 __attribute__((ext_vector_type(8)));
typedef float f32x4 __attribute__((ext_vector_type(4)));
typedef unsigned int uint32x2 __attribute__((ext_vector_type(2)));
typedef unsigned int uint32x4 __attribute__((ext_vector_type(4)));

#define B_SZ 4
#define SEQ 2048
#define NH 16
#define DH 64
#define DM 1024
#define RSQ (3 * DM)

// async global->LDS, 16B per lane. LDS dest = wave-uniform base + lane*16.
__device__ __forceinline__ void gload_lds16(const bf16_t* g, bf16_t* l) {
  __builtin_amdgcn_global_load_lds(
      (const __attribute__((address_space(1))) unsigned int*)g,
      (__attribute__((address_space(3))) unsigned int*)l, 16, 0, 0);
}

__device__ __forceinline__ unsigned lds_b32addr(void* p) {
  return (unsigned)(uintptr_t)(__attribute__((address_space(3))) void*)p;
}

// ---------------------------------------------------------------------------
// fp32 -> bf16 elementwise convert, 4 elems/thread.
// ---------------------------------------------------------------------------
__global__ __launch_bounds__(256) void f32_to_bf16_kernel(
    const float* __restrict__ in, bf16_t* __restrict__ out, int n) {
  int i = (blockIdx.x * blockDim.x + threadIdx.x) * 4;
  if (i >= n) return;
  float4 v = *reinterpret_cast<const float4*>(in + i);
  bf16_t o[4] = {(bf16_t)v.x, (bf16_t)v.y, (bf16_t)v.z, (bf16_t)v.w};
  *reinterpret_cast<uint2*>(out + i) = *reinterpret_cast<const uint2*>(o);
}

// ---------------------------------------------------------------------------
// fp32 [K][N] -> bf16 transposed [N][K], output rows < scale_cols scaled.
// ---------------------------------------------------------------------------
__global__ __launch_bounds__(256) void transpose_f32_bf16_kernel(
    const float* __restrict__ in, bf16_t* __restrict__ outT, int K, int N,
    int scale_cols, float scale) {
  __shared__ float tile[32][33];
  const int tx = threadIdx.x & 31;
  const int ty = threadIdx.x >> 5;  // 0..7
  const int n0 = blockIdx.x * 32;
  const int k0 = blockIdx.y * 32;
#pragma unroll
  for (int j = 0; j < 4; ++j)
    tile[ty + j * 8][tx] = in[(size_t)(k0 + ty + j * 8) * N + n0 + tx];
  __syncthreads();
#pragma unroll
  for (int j = 0; j < 4; ++j) {
    int n = n0 + ty + j * 8;
    float s = (n < scale_cols) ? scale : 1.0f;
    outT[(size_t)n * K + k0 + tx] = (bf16_t)(tile[tx][ty + j * 8] * s);
  }
}

// ---------------------------------------------------------------------------
// Deep-pipelined GEMM: C[M,N] = A[M,K] @ Bt[N,K]^T. bf16 in, OutT out.
// BM=128, BN=256, BK=64. 512 threads = 8 waves (2M x 4N), per-wave 64x64.
// Triple-buffered LDS (144 KiB): body t reads tile t, stages tile t+2
// (~2-tile / >700cyc prefetch lead), one s_barrier + counted vmcnt(6)/tile.
// XOR swizzle (chunk ^= row&7, 16B chunks in each 128B row-slice): staged via
// pre-swizzled GLOBAL source col (gload_lds dest linear, rule 21), read with
// per-lane XOR -> 2-way conflicts only.
// ---------------------------------------------------------------------------
template <typename OutT>
__global__ __launch_bounds__(512, 2) void gemm_dp_kernel(
    const bf16_t* __restrict__ A, const bf16_t* __restrict__ Bt,
    OutT* __restrict__ C, int M, int N, int K, int NB) {
  __shared__ __align__(16) bf16_t As[3][128 * 64];  // 48 KiB
  __shared__ __align__(16) bf16_t Bs[3][256 * 64];  // 96 KiB

  const int tid = threadIdx.x;
  const int lane = tid & 63;
  const int wid = tid >> 6;  // 0..7
  const int l16 = lane & 15;
  const int g4 = lane >> 4;
  const int wm = wid >> 2;   // 0..1
  const int wn = wid & 3;    // 0..3
  const int tiles = K >> 6;  // K-tiles of 64

  // XCD swizzle (nwg % 8 == 0 for both shapes)
  const int nwg = gridDim.x;
  const int bid = blockIdx.x;
  const int swz = (bid & 7) * (nwg >> 3) + (bid >> 3);
  const int m0 = (swz / NB) * 128;
  const int n0 = (swz % NB) * 256;

  // ---- staging maps: inst i covers rows i*64 + (tid>>3), 8 lanes x 8 elems
  // per row; LDS dest linear (elem = i*4096 + tid*8). Source col pre-swizzled
  // so that LDS chunk c holds logical chunk c ^ (row&7).
  const int srow = tid >> 3;                              // 0..63
  const int scol = ((tid & 7) ^ (srow & 7)) * 8;          // swizzled source
  const bf16_t* aglob = A + (size_t)(m0 + srow) * K + scol;
  const bf16_t* bglob = Bt + (size_t)(n0 + srow) * K + scol;

  auto stage = [&](int t) {
    const int buf = t % 3;
    const int k0 = t * 64;
#pragma unroll
    for (int i = 0; i < 2; ++i)
      gload_lds16(aglob + (size_t)i * 64 * K + k0,
                  &As[buf][i * 4096 + wid * 512]);
#pragma unroll
    for (int j = 0; j < 4; ++j)
      gload_lds16(bglob + (size_t)j * 64 * K + k0,
                  &Bs[buf][j * 4096 + wid * 512]);
  };

  f32x4 acc[4][4] = {};

  // ---- prologue: stage tiles 0,1 (12 loads); wait tile 0 (6 remain)
  stage(0);
  stage(1);
  asm volatile("s_waitcnt vmcnt(6)" ::: "memory");
  __builtin_amdgcn_s_barrier();
  __builtin_amdgcn_sched_barrier(0);

  const int xr = l16 & 7;  // read-side swizzle key (row&7 == l16&7)

  for (int t = 0; t < tiles; ++t) {
    const int buf = t % 3;

    // ---- ds_read 16 swizzled b128 fragments of tile t
    bf16x8 af[4][2], bff[4][2];
#pragma unroll
    for (int m = 0; m < 4; ++m)
#pragma unroll
      for (int ks = 0; ks < 2; ++ks)
        af[m][ks] = *reinterpret_cast<const bf16x8*>(
            &As[buf][(wm * 64 + m * 16 + l16) * 64 +
                     ((ks * 4 + g4) ^ xr) * 8]);
#pragma unroll
    for (int n = 0; n < 4; ++n)
#pragma unroll
      for (int ks = 0; ks < 2; ++ks)
        bff[n][ks] = *reinterpret_cast<const bf16x8*>(
            &Bs[buf][(wn * 64 + n * 16 + l16) * 64 +
                     ((ks * 4 + g4) ^ xr) * 8]);

    // ---- stage tile t+2 (6 loads; lands ~2 tiles later)
    if (t + 2 < tiles) stage(t + 2);

    // ---- 32 MFMA (compiler inserts lgkmcnt for the ds_reads)
    __builtin_amdgcn_s_setprio(1);
#pragma unroll
    for (int m = 0; m < 4; ++m)
#pragma unroll
      for (int n = 0; n < 4; ++n)
#pragma unroll
        for (int ks = 0; ks < 2; ++ks)
          acc[m][n] = __builtin_amdgcn_mfma_f32_16x16x32_bf16(
              af[m][ks], bff[n][ks], acc[m][n], 0, 0, 0);
    __builtin_amdgcn_s_setprio(0);

    // ---- wait tile t+1 landed (t+2's 6 stay in flight); barrier
    if (t + 2 < tiles)
      asm volatile("s_waitcnt vmcnt(6)" ::: "memory");
    else
      asm volatile("s_waitcnt vmcnt(0)" ::: "memory");
    __builtin_amdgcn_s_barrier();
    __builtin_amdgcn_sched_barrier(0);
  }

  // ---- epilogue: C/D layout col=l16, row=g4*4+r
#pragma unroll
  for (int m = 0; m < 4; ++m)
#pragma unroll
    for (int n = 0; n < 4; ++n)
#pragma unroll
      for (int r = 0; r < 4; ++r) {
        int row = m0 + wm * 64 + m * 16 + g4 * 4 + r;
        int col = n0 + wn * 64 + n * 16 + l16;
        C[(size_t)row * N + col] = (OutT)acc[m][n][r];
      }
}

// ---------------------------------------------------------------------------
// Flash attention body (round-6 version): one 128-key step.
//   [asm K(i) loads][stage V(i+1) -> other buf][vmcnt(8): V(i) landed]
//   [tr_read V(i)][vmcnt(4): K(i) ready, V(i+1) in flight][QK][exp][PV]
// Q pre-scaled by 0.125*log2(e) in w_qkv -> exp2 directly.
// ---------------------------------------------------------------------------
template <bool PRE>
__device__ __forceinline__ void attn_body(
    const bf16_t* kp, const bf16_t* vp_next, bf16_t* vst_next, unsigned vrd,
    const bf16x8 (&qf)[4][2], f32x4 (&acc_o)[16], float (&lsum)[4]) {
  uint32x4 kf[2][2];
#pragma unroll
  for (int half = 0; half < 2; ++half)
#pragma unroll
    for (int kh = 0; kh < 2; ++kh)
      asm volatile("global_load_dwordx4 %0, %1, off"
                   : "=v"(kf[half][kh])
                   : "v"(kp + (size_t)half * 64 * RSQ + kh * 32)
                   : "memory");

  if constexpr (PRE) {
#pragma unroll
    for (int t = 0; t < 4; ++t)
      gload_lds16(vp_next + t * 16, vst_next + t * 512);
  }

  if constexpr (PRE)
    asm volatile("s_waitcnt vmcnt(8)" ::: "memory");
  else
    asm volatile("s_waitcnt vmcnt(4)" ::: "memory");

  uint32x2 vr[4][2];
#define TRR(dst, OFFSTR)                              \
  asm volatile("ds_read_b64_tr_b16 %0, %1 offset:" OFFSTR \
               : "=v"(dst)                            \
               : "v"(vrd))
  TRR(vr[0][0], "0");    TRR(vr[0][1], "512");
  TRR(vr[1][0], "1024"); TRR(vr[1][1], "1536");
  TRR(vr[2][0], "2048"); TRR(vr[2][1], "2560");
  TRR(vr[3][0], "3072"); TRR(vr[3][1], "3584");
#undef TRR

  if constexpr (PRE)
    asm volatile("s_waitcnt vmcnt(4)" ::: "memory");
  else
    asm volatile("s_waitcnt vmcnt(0)" ::: "memory");
  __builtin_amdgcn_sched_barrier(0);  // rule 18

  f32x4 sA[4] = {}, sB[4] = {};
#pragma unroll
  for (int qb = 0; qb < 4; ++qb) {
    sA[qb] = __builtin_amdgcn_mfma_f32_16x16x32_bf16(
        __builtin_bit_cast(bf16x8, kf[0][0]), qf[qb][0], sA[qb], 0, 0, 0);
    sA[qb] = __builtin_amdgcn_mfma_f32_16x16x32_bf16(
        __builtin_bit_cast(bf16x8, kf[0][1]), qf[qb][1], sA[qb], 0, 0, 0);
    sB[qb] = __builtin_amdgcn_mfma_f32_16x16x32_bf16(
        __builtin_bit_cast(bf16x8, kf[1][0]), qf[qb][0], sB[qb], 0, 0, 0);
    sB[qb] = __builtin_amdgcn_mfma_f32_16x16x32_bf16(
        __builtin_bit_cast(bf16x8, kf[1][1]), qf[qb][1], sB[qb], 0, 0, 0);
  }

  bf16x8 pf[4];
#pragma unroll
  for (int qb = 0; qb < 4; ++qb) {
    float p0 = __builtin_amdgcn_exp2f(sA[qb][0]);
    float p1 = __builtin_amdgcn_exp2f(sA[qb][1]);
    float p2 = __builtin_amdgcn_exp2f(sA[qb][2]);
    float p3 = __builtin_amdgcn_exp2f(sA[qb][3]);
    float p4 = __builtin_amdgcn_exp2f(sB[qb][0]);
    float p5 = __builtin_amdgcn_exp2f(sB[qb][1]);
    float p6 = __builtin_amdgcn_exp2f(sB[qb][2]);
    float p7 = __builtin_amdgcn_exp2f(sB[qb][3]);
    lsum[qb] += ((p0 + p1) + (p2 + p3)) + ((p4 + p5) + (p6 + p7));
    pf[qb][0] = (bf16_t)p0; pf[qb][1] = (bf16_t)p1;
    pf[qb][2] = (bf16_t)p2; pf[qb][3] = (bf16_t)p3;
    pf[qb][4] = (bf16_t)p4; pf[qb][5] = (bf16_t)p5;
    pf[qb][6] = (bf16_t)p6; pf[qb][7] = (bf16_t)p7;
  }

  asm volatile("s_waitcnt lgkmcnt(0)" ::: "memory");
  __builtin_amdgcn_sched_barrier(0);
  bf16x8 vf[4];
#pragma unroll
  for (int db = 0; db < 4; ++db) {
    uint32x4 c = {vr[db][0].x, vr[db][0].y, vr[db][1].x, vr[db][1].y};
    vf[db] = __builtin_bit_cast(bf16x8, c);
  }
#pragma unroll
  for (int qb = 0; qb < 4; ++qb)
#pragma unroll
    for (int db = 0; db < 4; ++db)
      acc_o[qb * 4 + db] = __builtin_amdgcn_mfma_f32_16x16x32_bf16(
          pf[qb], vf[db], acc_o[qb * 4 + db], 0, 0, 0);
}

// ---------------------------------------------------------------------------
__global__ __launch_bounds__(256) void attn_kernel(
    const bf16_t* __restrict__ qkv, bf16_t* __restrict__ out) {
  __shared__ __align__(16) unsigned char smem[33792];
  bf16_t* Vlds = (bf16_t*)smem;            // [4 waves][2 bufs][2048] = 32 KiB
  float(*Obuf)[66] = (float(*)[66])smem;   // aliases Vlds (k-loop finished)
  float* lbuf = (float*)(smem + 32768);    // [4][64] floats

  const int tid = threadIdx.x;
  const int lane = tid & 63;
  const int wid = tid >> 6;
  const int l16 = lane & 15;
  const int g4 = lane >> 4;

  const int D = blockIdx.x;
  const int g = ((D >> 8) << 3) + (D & 7);
  const int h = g & 15;
  const int b = g >> 4;
  const int q0 = ((D >> 3) & 31) * 64;

  const size_t base = (size_t)b * SEQ * RSQ;

  bf16x8 qf[4][2];
#pragma unroll
  for (int qb = 0; qb < 4; ++qb)
#pragma unroll
    for (int kh = 0; kh < 2; ++kh)
      qf[qb][kh] = __builtin_bit_cast(
          bf16x8, *reinterpret_cast<const uint4*>(
                      qkv + base + (size_t)(q0 + qb * 16 + l16) * RSQ + h * DH +
                      kh * 32 + g4 * 8));

  const bf16_t* kbase =
      qkv + base + (size_t)(wid * 16 + l16) * RSQ + DM + h * DH + g4 * 8;

  const int keyoff = ((lane >> 5) << 6) + wid * 16 + (((lane >> 3) & 3) << 2) +
                     ((lane >> 1) & 3);
  const bf16_t* vsrc =
      qkv + base + (size_t)keyoff * RSQ + 2 * DM + h * DH + (lane & 1) * 8;
  bf16_t* vwave = Vlds + wid * 4096;  // 2 buffers of 2048
  const unsigned vlane = lds_b32addr(vwave) + (lane << 3);

  f32x4 acc_o[16] = {};
  float lsum[4] = {0.f, 0.f, 0.f, 0.f};

#pragma unroll
  for (int t = 0; t < 4; ++t) gload_lds16(vsrc + t * 16, vwave + t * 512);

  for (int i = 0; i < 15; ++i) {
    const bf16_t* kp = kbase + (size_t)i * 128 * RSQ;
    const bf16_t* vp_next = vsrc + (size_t)(i + 1) * 128 * RSQ;
    bf16_t* vst_next = vwave + ((i + 1) & 1) * 2048;
    unsigned vrd = vlane + (i & 1) * 4096;
    attn_body<true>(kp, vp_next, vst_next, vrd, qf, acc_o, lsum);
  }
  attn_body<false>(kbase + (size_t)15 * 128 * RSQ, nullptr, nullptr,
                   vlane + 4096, qf, acc_o, lsum);

#pragma unroll
  for (int qb = 0; qb < 4; ++qb) {
    float t = lsum[qb];
    t += __shfl_xor(t, 16, 64);
    t += __shfl_xor(t, 32, 64);
    if (g4 == 0) lbuf[wid * 64 + qb * 16 + l16] = t;
  }

  for (int ph = 0; ph < 4; ++ph) {
    __syncthreads();
    if (wid == ph) {
#pragma unroll
      for (int qb = 0; qb < 4; ++qb)
#pragma unroll
        for (int db = 0; db < 4; ++db)
#pragma unroll
          for (int r = 0; r < 4; ++r) {
            int q = qb * 16 + g4 * 4 + r;
            int d = db * 16 + l16;
            if (ph == 0)
              Obuf[q][d] = acc_o[qb * 4 + db][r];
            else
              Obuf[q][d] += acc_o[qb * 4 + db][r];
          }
    }
  }
  __syncthreads();

  {
    int q = wid * 16 + l16;
    float l = lbuf[0 * 64 + q] + lbuf[1 * 64 + q] + lbuf[2 * 64 + q] +
              lbuf[3 * 64 + q];
    float inv = 1.f / l;
    bf16_t ob[16];
#pragma unroll
    for (int c = 0; c < 16; ++c)
      ob[c] = (bf16_t)(Obuf[q][g4 * 16 + c] * inv);
    bf16_t* op = out + (size_t)(b * SEQ + q0 + q) * DM + h * DH + g4 * 16;
    *reinterpret_cast<uint4*>(op) = *reinterpret_cast<const uint4*>(&ob[0]);
    *reinterpret_cast<uint4*>(op + 8) = *reinterpret_cast<const uint4*>(&ob[8]);
  }
}

// ---------------------------------------------------------------------------
extern "C" void kernel_launch(void* const* d_in, const int* in_sizes, int n_in,
                              void* d_out, int out_size, void* d_ws, size_t ws_size,
                              hipStream_t stream) {
  const float* x = (const float*)d_in[0];       // [4,2048,1024] fp32
  const float* w_qkv = (const float*)d_in[1];   // [1024,3072] fp32
  const float* w_o = (const float*)d_in[2];     // [1024,1024] fp32
  float* out = (float*)d_out;                   // [4,2048,1024] fp32

  bf16_t* xb = (bf16_t*)d_ws;                        // [8192][1024]
  bf16_t* wqkvt = xb + (size_t)8192 * 1024;          // [3072][1024]
  bf16_t* wot = wqkvt + (size_t)3072 * 1024;         // [1024][1024]
  bf16_t* qkv = wot + (size_t)1024 * 1024;           // [8192][3072]
  bf16_t* attn = qkv + (size_t)8192 * 3072;          // [8192][1024]

  const float c_exp2 = 0.18033688011112042f;  // 0.125 * log2(e)

  f32_to_bf16_kernel<<<8192, 256, 0, stream>>>(x, xb, 8192 * 1024);
  transpose_f32_bf16_kernel<<<dim3(3072 / 32, 1024 / 32), 256, 0, stream>>>(
      w_qkv, wqkvt, 1024, 3072, 1024, c_exp2);
  transpose_f32_bf16_kernel<<<dim3(1024 / 32, 1024 / 32), 256, 0, stream>>>(
      w_o, wot, 1024, 1024, 0, 1.0f);

  // qkv = x @ w_qkv : 64x12 = 768 blocks (3 exact CU rounds)
  gemm_dp_kernel<bf16_t><<<768, 512, 0, stream>>>(
      xb, wqkvt, qkv, 8192, 3072, 1024, 12);
  attn_kernel<<<2048, 256, 0, stream>>>(qkv, attn);
  // out = attn @ w_o : 64x4 = 256 blocks (1 exact CU round)
  gemm_dp_kernel<float><<<256, 512, 0, stream>>>(
      attn, wot, out, 8192, 1024, 1024, 4);
}

// Round 10
// 220.118 us; speedup vs baseline: 1.1421x; 1.0154x over previous
//
#include <hip/hip_runtime.h>
#include <hip/hip_bf16.h>

typedef __bf16 bf16_t;
typedef __bf16 bf16x8 __attribute__((ext_vector_type(8)));
typedef float f32x4 __attribute__((ext_vector_type(4)));
typedef unsigned int uint32x2 __attribute__((ext_vector_type(2)));
typedef unsigned int uint32x4 __attribute__((ext_vector_type(4)));

#define B_SZ 4
#define SEQ 2048
#define NH 16
#define DH 64
#define DM 1024
#define RSQ (3 * DM)

// async global->LDS, 16B per lane. LDS dest = wave-uniform base + lane*16.
__device__ __forceinline__ void gload_lds16(const bf16_t* g, bf16_t* l) {
  __builtin_amdgcn_global_load_lds(
      (const __attribute__((address_space(1))) unsigned int*)g,
      (__attribute__((address_space(3))) unsigned int*)l, 16, 0, 0);
}

__device__ __forceinline__ unsigned lds_b32addr(void* p) {
  return (unsigned)(uintptr_t)(__attribute__((address_space(3))) void*)p;
}

// ---------------------------------------------------------------------------
// fp32 -> bf16 elementwise convert, 4 elems/thread.
// ---------------------------------------------------------------------------
__global__ __launch_bounds__(256) void f32_to_bf16_kernel(
    const float* __restrict__ in, bf16_t* __restrict__ out, int n) {
  int i = (blockIdx.x * blockDim.x + threadIdx.x) * 4;
  if (i >= n) return;
  float4 v = *reinterpret_cast<const float4*>(in + i);
  bf16_t o[4] = {(bf16_t)v.x, (bf16_t)v.y, (bf16_t)v.z, (bf16_t)v.w};
  *reinterpret_cast<uint2*>(out + i) = *reinterpret_cast<const uint2*>(o);
}

// ---------------------------------------------------------------------------
// fp32 [K][N] -> bf16 transposed [N][K], output rows < scale_cols scaled.
// ---------------------------------------------------------------------------
__global__ __launch_bounds__(256) void transpose_f32_bf16_kernel(
    const float* __restrict__ in, bf16_t* __restrict__ outT, int K, int N,
    int scale_cols, float scale) {
  __shared__ float tile[32][33];
  const int tx = threadIdx.x & 31;
  const int ty = threadIdx.x >> 5;  // 0..7
  const int n0 = blockIdx.x * 32;
  const int k0 = blockIdx.y * 32;
#pragma unroll
  for (int j = 0; j < 4; ++j)
    tile[ty + j * 8][tx] = in[(size_t)(k0 + ty + j * 8) * N + n0 + tx];
  __syncthreads();
#pragma unroll
  for (int j = 0; j < 4; ++j) {
    int n = n0 + ty + j * 8;
    float s = (n < scale_cols) ? scale : 1.0f;
    outT[(size_t)n * K + k0 + tx] = (bf16_t)(tile[tx][ty + j * 8] * s);
  }
}

// ---------------------------------------------------------------------------
// Deep-pipelined GEMM: C[M,N] = A[M,K] @ Bt[N,K]^T. bf16 in, OutT out.
// BM=128, BN=256, BK=64. 512 threads = 8 waves (2M x 4N), per-wave 64x64.
// Triple-buffered LDS, 2-tile prefetch lead, one s_barrier + vmcnt(6)/tile,
// both-sides XOR swizzle (rule 21). (unchanged from round 9)
// ---------------------------------------------------------------------------
template <typename OutT>
__global__ __launch_bounds__(512, 2) void gemm_dp_kernel(
    const bf16_t* __restrict__ A, const bf16_t* __restrict__ Bt,
    OutT* __restrict__ C, int M, int N, int K, int NB) {
  __shared__ __align__(16) bf16_t As[3][128 * 64];  // 48 KiB
  __shared__ __align__(16) bf16_t Bs[3][256 * 64];  // 96 KiB

  const int tid = threadIdx.x;
  const int lane = tid & 63;
  const int wid = tid >> 6;  // 0..7
  const int l16 = lane & 15;
  const int g4 = lane >> 4;
  const int wm = wid >> 2;   // 0..1
  const int wn = wid & 3;    // 0..3
  const int tiles = K >> 6;  // K-tiles of 64

  const int nwg = gridDim.x;
  const int bid = blockIdx.x;
  const int swz = (bid & 7) * (nwg >> 3) + (bid >> 3);
  const int m0 = (swz / NB) * 128;
  const int n0 = (swz % NB) * 256;

  const int srow = tid >> 3;                              // 0..63
  const int scol = ((tid & 7) ^ (srow & 7)) * 8;          // swizzled source
  const bf16_t* aglob = A + (size_t)(m0 + srow) * K + scol;
  const bf16_t* bglob = Bt + (size_t)(n0 + srow) * K + scol;

  auto stage = [&](int t) {
    const int buf = t % 3;
    const int k0 = t * 64;
#pragma unroll
    for (int i = 0; i < 2; ++i)
      gload_lds16(aglob + (size_t)i * 64 * K + k0,
                  &As[buf][i * 4096 + wid * 512]);
#pragma unroll
    for (int j = 0; j < 4; ++j)
      gload_lds16(bglob + (size_t)j * 64 * K + k0,
                  &Bs[buf][j * 4096 + wid * 512]);
  };

  f32x4 acc[4][4] = {};

  stage(0);
  stage(1);
  asm volatile("s_waitcnt vmcnt(6)" ::: "memory");
  __builtin_amdgcn_s_barrier();
  __builtin_amdgcn_sched_barrier(0);

  const int xr = l16 & 7;  // read-side swizzle key

  for (int t = 0; t < tiles; ++t) {
    const int buf = t % 3;

    bf16x8 af[4][2], bff[4][2];
#pragma unroll
    for (int m = 0; m < 4; ++m)
#pragma unroll
      for (int ks = 0; ks < 2; ++ks)
        af[m][ks] = *reinterpret_cast<const bf16x8*>(
            &As[buf][(wm * 64 + m * 16 + l16) * 64 +
                     ((ks * 4 + g4) ^ xr) * 8]);
#pragma unroll
    for (int n = 0; n < 4; ++n)
#pragma unroll
      for (int ks = 0; ks < 2; ++ks)
        bff[n][ks] = *reinterpret_cast<const bf16x8*>(
            &Bs[buf][(wn * 64 + n * 16 + l16) * 64 +
                     ((ks * 4 + g4) ^ xr) * 8]);

    if (t + 2 < tiles) stage(t + 2);

    __builtin_amdgcn_s_setprio(1);
#pragma unroll
    for (int m = 0; m < 4; ++m)
#pragma unroll
      for (int n = 0; n < 4; ++n)
#pragma unroll
        for (int ks = 0; ks < 2; ++ks)
          acc[m][n] = __builtin_amdgcn_mfma_f32_16x16x32_bf16(
              af[m][ks], bff[n][ks], acc[m][n], 0, 0, 0);
    __builtin_amdgcn_s_setprio(0);

    if (t + 2 < tiles)
      asm volatile("s_waitcnt vmcnt(6)" ::: "memory");
    else
      asm volatile("s_waitcnt vmcnt(0)" ::: "memory");
    __builtin_amdgcn_s_barrier();
    __builtin_amdgcn_sched_barrier(0);
  }

#pragma unroll
  for (int m = 0; m < 4; ++m)
#pragma unroll
    for (int n = 0; n < 4; ++n)
#pragma unroll
      for (int r = 0; r < 4; ++r) {
        int row = m0 + wm * 64 + m * 16 + g4 * 4 + r;
        int col = n0 + wn * 64 + n * 16 + l16;
        C[(size_t)row * N + col] = (OutT)acc[m][n][r];
      }
}

// ---------------------------------------------------------------------------
// Flash attention body: one 128-key step, K issued LATE (post-QK) so both K
// and V have a full-iteration prefetch lead with a single kf register set.
// Invariant at body entry: in-flight = [V(i) (older), K(i)] (8 ops).
//   A. stage V(i+1)                 -> 12 in flight
//   B. vmcnt(8): V(i) landed        (K(i), V(i+1) stay)
//   C. tr_read V(i)
//   D. vmcnt(4): K(i) in regs       (V(i+1) stays)
//   E. QK (consumes kf)
//   F. issue K(i+1) -> kf regs (dead after E)  -> invariant restored
//   G. exp2 -> pf ; H. lgkm(0); PV
// ---------------------------------------------------------------------------
template <bool PRE>
__device__ __forceinline__ void attn_body(
    const bf16_t* kp_next, const bf16_t* vp_next, bf16_t* vst_next,
    unsigned vrd, uint32x4 (&kf)[2][2], const bf16x8 (&qf)[4][2],
    f32x4 (&acc_o)[16], float (&lsum)[4]) {
  // ---- A. stage V(i+1) (wave-private, async, zero VGPR)
  if constexpr (PRE) {
#pragma unroll
    for (int t = 0; t < 4; ++t)
      gload_lds16(vp_next + t * 16, vst_next + t * 512);
  }

  // ---- B. V(i) landed (issued one body earlier; V older than K)
  if constexpr (PRE)
    asm volatile("s_waitcnt vmcnt(8)" ::: "memory");
  else
    asm volatile("s_waitcnt vmcnt(4)" ::: "memory");
  __builtin_amdgcn_sched_barrier(0);

  // ---- C. V(i) B-frags via HW transpose read (per-lane addr = base+lane*8)
  uint32x2 vr[4][2];
#define TRR(dst, OFFSTR)                              \
  asm volatile("ds_read_b64_tr_b16 %0, %1 offset:" OFFSTR \
               : "=v"(dst)                            \
               : "v"(vrd))
  TRR(vr[0][0], "0");    TRR(vr[0][1], "512");
  TRR(vr[1][0], "1024"); TRR(vr[1][1], "1536");
  TRR(vr[2][0], "2048"); TRR(vr[2][1], "2560");
  TRR(vr[3][0], "3072"); TRR(vr[3][1], "3584");
#undef TRR

  // ---- D. K(i) ready (issued one body earlier, full-iter lead)
  if constexpr (PRE)
    asm volatile("s_waitcnt vmcnt(4)" ::: "memory");
  else
    asm volatile("s_waitcnt vmcnt(0)" ::: "memory");
  __builtin_amdgcn_sched_barrier(0);  // rule 18

  // ---- E. swapped QK^T: s[key][q] (Q pre-scaled)
  f32x4 sA[4] = {}, sB[4] = {};
#pragma unroll
  for (int qb = 0; qb < 4; ++qb) {
    sA[qb] = __builtin_amdgcn_mfma_f32_16x16x32_bf16(
        __builtin_bit_cast(bf16x8, kf[0][0]), qf[qb][0], sA[qb], 0, 0, 0);
    sA[qb] = __builtin_amdgcn_mfma_f32_16x16x32_bf16(
        __builtin_bit_cast(bf16x8, kf[0][1]), qf[qb][1], sA[qb], 0, 0, 0);
    sB[qb] = __builtin_amdgcn_mfma_f32_16x16x32_bf16(
        __builtin_bit_cast(bf16x8, kf[1][0]), qf[qb][0], sB[qb], 0, 0, 0);
    sB[qb] = __builtin_amdgcn_mfma_f32_16x16x32_bf16(
        __builtin_bit_cast(bf16x8, kf[1][1]), qf[qb][1], sB[qb], 0, 0, 0);
  }

  // ---- F. issue K(i+1) into kf (registers dead after E)
  if constexpr (PRE) {
#pragma unroll
    for (int half = 0; half < 2; ++half)
#pragma unroll
      for (int kh = 0; kh < 2; ++kh)
        asm volatile("global_load_dwordx4 %0, %1, off"
                     : "=v"(kf[half][kh])
                     : "v"(kp_next + (size_t)half * 64 * RSQ + kh * 32)
                     : "memory");
  }

  // ---- G. exp2 + lsum + pack to PV A-frags (keys lane-local)
  bf16x8 pf[4];
#pragma unroll
  for (int qb = 0; qb < 4; ++qb) {
    float p0 = __builtin_amdgcn_exp2f(sA[qb][0]);
    float p1 = __builtin_amdgcn_exp2f(sA[qb][1]);
    float p2 = __builtin_amdgcn_exp2f(sA[qb][2]);
    float p3 = __builtin_amdgcn_exp2f(sA[qb][3]);
    float p4 = __builtin_amdgcn_exp2f(sB[qb][0]);
    float p5 = __builtin_amdgcn_exp2f(sB[qb][1]);
    float p6 = __builtin_amdgcn_exp2f(sB[qb][2]);
    float p7 = __builtin_amdgcn_exp2f(sB[qb][3]);
    lsum[qb] += ((p0 + p1) + (p2 + p3)) + ((p4 + p5) + (p6 + p7));
    pf[qb][0] = (bf16_t)p0; pf[qb][1] = (bf16_t)p1;
    pf[qb][2] = (bf16_t)p2; pf[qb][3] = (bf16_t)p3;
    pf[qb][4] = (bf16_t)p4; pf[qb][5] = (bf16_t)p5;
    pf[qb][6] = (bf16_t)p6; pf[qb][7] = (bf16_t)p7;
  }

  // ---- H. tr_reads complete; build vf; PV
  asm volatile("s_waitcnt lgkmcnt(0)" ::: "memory");
  __builtin_amdgcn_sched_barrier(0);
  bf16x8 vf[4];
#pragma unroll
  for (int db = 0; db < 4; ++db) {
    uint32x4 c = {vr[db][0].x, vr[db][0].y, vr[db][1].x, vr[db][1].y};
    vf[db] = __builtin_bit_cast(bf16x8, c);
  }
#pragma unroll
  for (int qb = 0; qb < 4; ++qb)
#pragma unroll
    for (int db = 0; db < 4; ++db)
      acc_o[qb * 4 + db] = __builtin_amdgcn_mfma_f32_16x16x32_bf16(
          pf[qb], vf[db], acc_o[qb * 4 + db], 0, 0, 0);
}

// ---------------------------------------------------------------------------
__global__ __launch_bounds__(256) void attn_kernel(
    const bf16_t* __restrict__ qkv, bf16_t* __restrict__ out) {
  __shared__ __align__(16) unsigned char smem[33792];
  bf16_t* Vlds = (bf16_t*)smem;            // [4 waves][2 bufs][2048] = 32 KiB
  float(*Obuf)[66] = (float(*)[66])smem;   // aliases Vlds (k-loop finished)
  float* lbuf = (float*)(smem + 32768);    // [4][64] floats

  const int tid = threadIdx.x;
  const int lane = tid & 63;
  const int wid = tid >> 6;
  const int l16 = lane & 15;
  const int g4 = lane >> 4;

  // XCD-aware decode: all 32 q-tiles of one (b,h) on one XCD
  const int D = blockIdx.x;
  const int g = ((D >> 8) << 3) + (D & 7);
  const int h = g & 15;
  const int b = g >> 4;
  const int q0 = ((D >> 3) & 31) * 64;

  const size_t base = (size_t)b * SEQ * RSQ;

  // ---- Q fragments (pre-scaled by 0.125*log2e via w_qkv), hoisted
  bf16x8 qf[4][2];
#pragma unroll
  for (int qb = 0; qb < 4; ++qb)
#pragma unroll
    for (int kh = 0; kh < 2; ++kh)
      qf[qb][kh] = __builtin_bit_cast(
          bf16x8, *reinterpret_cast<const uint4*>(
                      qkv + base + (size_t)(q0 + qb * 16 + l16) * RSQ + h * DH +
                      kh * 32 + g4 * 8));

  const bf16_t* kbase =
      qkv + base + (size_t)(wid * 16 + l16) * RSQ + DM + h * DH + g4 * 8;

  // V staging source (pre-swizzled: linear LDS == [db][eh][g4][j][l16])
  const int keyoff = ((lane >> 5) << 6) + wid * 16 + (((lane >> 3) & 3) << 2) +
                     ((lane >> 1) & 3);
  const bf16_t* vsrc =
      qkv + base + (size_t)keyoff * RSQ + 2 * DM + h * DH + (lane & 1) * 8;
  bf16_t* vwave = Vlds + wid * 4096;  // 2 buffers of 2048
  const unsigned vlane = lds_b32addr(vwave) + (lane << 3);

  f32x4 acc_o[16] = {};
  float lsum[4] = {0.f, 0.f, 0.f, 0.f};
  uint32x4 kf[2][2];

  // ---- prologue: stage V(0) FIRST (must be older than K(0)), then K(0)
#pragma unroll
  for (int t = 0; t < 4; ++t) gload_lds16(vsrc + t * 16, vwave + t * 512);
#pragma unroll
  for (int half = 0; half < 2; ++half)
#pragma unroll
    for (int kh = 0; kh < 2; ++kh)
      asm volatile("global_load_dwordx4 %0, %1, off"
                   : "=v"(kf[half][kh])
                   : "v"(kbase + (size_t)half * 64 * RSQ + kh * 32)
                   : "memory");

  // ---- pipelined k-loop: bodies 0..14 prefetch K(i+1)/V(i+1); body 15 drains
  for (int i = 0; i < 15; ++i) {
    attn_body<true>(kbase + (size_t)(i + 1) * 128 * RSQ,
                    vsrc + (size_t)(i + 1) * 128 * RSQ,
                    vwave + ((i + 1) & 1) * 2048, vlane + (i & 1) * 4096, kf,
                    qf, acc_o, lsum);
  }
  attn_body<false>(nullptr, nullptr, nullptr, vlane + 4096, kf, qf, acc_o,
                   lsum);

  // ---- l reduction: over g4 within wave, stash per-wave partials
#pragma unroll
  for (int qb = 0; qb < 4; ++qb) {
    float t = lsum[qb];
    t += __shfl_xor(t, 16, 64);
    t += __shfl_xor(t, 32, 64);
    if (g4 == 0) lbuf[wid * 64 + qb * 16 + l16] = t;
  }

  // ---- cross-wave O reduction (Obuf aliases Vlds; safe: vmem drained)
  for (int ph = 0; ph < 4; ++ph) {
    __syncthreads();
    if (wid == ph) {
#pragma unroll
      for (int qb = 0; qb < 4; ++qb)
#pragma unroll
        for (int db = 0; db < 4; ++db)
#pragma unroll
          for (int r = 0; r < 4; ++r) {
            int q = qb * 16 + g4 * 4 + r;
            int d = db * 16 + l16;
            if (ph == 0)
              Obuf[q][d] = acc_o[qb * 4 + db][r];
            else
              Obuf[q][d] += acc_o[qb * 4 + db][r];
          }
    }
  }
  __syncthreads();

  // ---- epilogue
  {
    int q = wid * 16 + l16;
    float l = lbuf[0 * 64 + q] + lbuf[1 * 64 + q] + lbuf[2 * 64 + q] +
              lbuf[3 * 64 + q];
    float inv = 1.f / l;
    bf16_t ob[16];
#pragma unroll
    for (int c = 0; c < 16; ++c)
      ob[c] = (bf16_t)(Obuf[q][g4 * 16 + c] * inv);
    bf16_t* op = out + (size_t)(b * SEQ + q0 + q) * DM + h * DH + g4 * 16;
    *reinterpret_cast<uint4*>(op) = *reinterpret_cast<const uint4*>(&ob[0]);
    *reinterpret_cast<uint4*>(op + 8) = *reinterpret_cast<const uint4*>(&ob[8]);
  }
}

// ---------------------------------------------------------------------------
extern "C" void kernel_launch(void* const* d_in, const int* in_sizes, int n_in,
                              void* d_out, int out_size, void* d_ws, size_t ws_size,
                              hipStream_t stream) {
  const float* x = (const float*)d_in[0];       // [4,2048,1024] fp32
  const float* w_qkv = (const float*)d_in[1];   // [1024,3072] fp32
  const float* w_o = (const float*)d_in[2];     // [1024,1024] fp32
  float* out = (float*)d_out;                   // [4,2048,1024] fp32

  bf16_t* xb = (bf16_t*)d_ws;                        // [8192][1024]
  bf16_t* wqkvt = xb + (size_t)8192 * 1024;          // [3072][1024]
  bf16_t* wot = wqkvt + (size_t)3072 * 1024;         // [1024][1024]
  bf16_t* qkv = wot + (size_t)1024 * 1024;           // [8192][3072]
  bf16_t* attn = qkv + (size_t)8192 * 3072;          // [8192][1024]

  const float c_exp2 = 0.18033688011112042f;  // 0.125 * log2(e)

  f32_to_bf16_kernel<<<8192, 256, 0, stream>>>(x, xb, 8192 * 1024);
  transpose_f32_bf16_kernel<<<dim3(3072 / 32, 1024 / 32), 256, 0, stream>>>(
      w_qkv, wqkvt, 1024, 3072, 1024, c_exp2);
  transpose_f32_bf16_kernel<<<dim3(1024 / 32, 1024 / 32), 256, 0, stream>>>(
      w_o, wot, 1024, 1024, 0, 1.0f);

  // qkv = x @ w_qkv : 64x12 = 768 blocks (3 exact CU rounds)
  gemm_dp_kernel<bf16_t><<<768, 512, 0, stream>>>(
      xb, wqkvt, qkv, 8192, 3072, 1024, 12);
  attn_kernel<<<2048, 256, 0, stream>>>(qkv, attn);
  // out = attn @ w_o : 64x4 = 256 blocks (1 exact CU round)
  gemm_dp_kernel<float><<<256, 512, 0, stream>>>(
      attn, wot, out, 8192, 1024, 1024, 4);
}

// Round 12
// 219.591 us; speedup vs baseline: 1.1448x; 1.0024x over previous
//
#include <hip/hip_runtime.h>
#include <hip/hip_bf16.h>

typedef __bf16 bf16_t;
typedef __bf16 bf16x8 __attribute__((ext_vector_type(8)));
typedef float f32x4 __attribute__((ext_vector_type(4)));
typedef unsigned int uint32x2 __attribute__((ext_vector_type(2)));
typedef unsigned int uint32x4 __attribute__((ext_vector_type(4)));

#define B_SZ 4
#define SEQ 2048
#define NH 16
#define DH 64
#define DM 1024
#define RSQ (3 * DM)

// async global->LDS, 16B per lane. LDS dest = wave-uniform base + lane*16.
__device__ __forceinline__ void gload_lds16(const bf16_t* g, bf16_t* l) {
  __builtin_amdgcn_global_load_lds(
      (const __attribute__((address_space(1))) unsigned int*)g,
      (__attribute__((address_space(3))) unsigned int*)l, 16, 0, 0);
}

__device__ __forceinline__ unsigned lds_b32addr(void* p) {
  return (unsigned)(uintptr_t)(__attribute__((address_space(3))) void*)p;
}

// ---------------------------------------------------------------------------
// fp32 -> bf16 elementwise convert, 4 elems/thread.
// ---------------------------------------------------------------------------
__global__ __launch_bounds__(256) void f32_to_bf16_kernel(
    const float* __restrict__ in, bf16_t* __restrict__ out, int n) {
  int i = (blockIdx.x * blockDim.x + threadIdx.x) * 4;
  if (i >= n) return;
  float4 v = *reinterpret_cast<const float4*>(in + i);
  bf16_t o[4] = {(bf16_t)v.x, (bf16_t)v.y, (bf16_t)v.z, (bf16_t)v.w};
  *reinterpret_cast<uint2*>(out + i) = *reinterpret_cast<const uint2*>(o);
}

// ---------------------------------------------------------------------------
// fp32 [K][N] -> bf16 transposed [N][K], output rows < scale_cols scaled.
// ---------------------------------------------------------------------------
__global__ __launch_bounds__(256) void transpose_f32_bf16_kernel(
    const float* __restrict__ in, bf16_t* __restrict__ outT, int K, int N,
    int scale_cols, float scale) {
  __shared__ float tile[32][33];
  const int tx = threadIdx.x & 31;
  const int ty = threadIdx.x >> 5;  // 0..7
  const int n0 = blockIdx.x * 32;
  const int k0 = blockIdx.y * 32;
#pragma unroll
  for (int j = 0; j < 4; ++j)
    tile[ty + j * 8][tx] = in[(size_t)(k0 + ty + j * 8) * N + n0 + tx];
  __syncthreads();
#pragma unroll
  for (int j = 0; j < 4; ++j) {
    int n = n0 + ty + j * 8;
    float s = (n < scale_cols) ? scale : 1.0f;
    outT[(size_t)n * K + k0 + tx] = (bf16_t)(tile[tx][ty + j * 8] * s);
  }
}

// ---------------------------------------------------------------------------
// Deep-pipelined GEMM: C[M,N] = A[M,K] @ Bt[N,K]^T. bf16 in, OutT out.
// BM=128, BN=256, BK=64. 512 threads = 8 waves (2M x 4N), per-wave 64x64.
// Triple-buffered LDS, 2-tile prefetch lead, one s_barrier + vmcnt(6)/tile,
// both-sides XOR swizzle (rule 21). (unchanged from round 9)
// ---------------------------------------------------------------------------
template <typename OutT>
__global__ __launch_bounds__(512, 2) void gemm_dp_kernel(
    const bf16_t* __restrict__ A, const bf16_t* __restrict__ Bt,
    OutT* __restrict__ C, int M, int N, int K, int NB) {
  __shared__ __align__(16) bf16_t As[3][128 * 64];  // 48 KiB
  __shared__ __align__(16) bf16_t Bs[3][256 * 64];  // 96 KiB

  const int tid = threadIdx.x;
  const int lane = tid & 63;
  const int wid = tid >> 6;  // 0..7
  const int l16 = lane & 15;
  const int g4 = lane >> 4;
  const int wm = wid >> 2;   // 0..1
  const int wn = wid & 3;    // 0..3
  const int tiles = K >> 6;  // K-tiles of 64

  const int nwg = gridDim.x;
  const int bid = blockIdx.x;
  const int swz = (bid & 7) * (nwg >> 3) + (bid >> 3);
  const int m0 = (swz / NB) * 128;
  const int n0 = (swz % NB) * 256;

  const int srow = tid >> 3;                              // 0..63
  const int scol = ((tid & 7) ^ (srow & 7)) * 8;          // swizzled source
  const bf16_t* aglob = A + (size_t)(m0 + srow) * K + scol;
  const bf16_t* bglob = Bt + (size_t)(n0 + srow) * K + scol;

  auto stage = [&](int t) {
    const int buf = t % 3;
    const int k0 = t * 64;
#pragma unroll
    for (int i = 0; i < 2; ++i)
      gload_lds16(aglob + (size_t)i * 64 * K + k0,
                  &As[buf][i * 4096 + wid * 512]);
#pragma unroll
    for (int j = 0; j < 4; ++j)
      gload_lds16(bglob + (size_t)j * 64 * K + k0,
                  &Bs[buf][j * 4096 + wid * 512]);
  };

  f32x4 acc[4][4] = {};

  stage(0);
  stage(1);
  asm volatile("s_waitcnt vmcnt(6)" ::: "memory");
  __builtin_amdgcn_s_barrier();
  __builtin_amdgcn_sched_barrier(0);

  const int xr = l16 & 7;  // read-side swizzle key

  for (int t = 0; t < tiles; ++t) {
    const int buf = t % 3;

    bf16x8 af[4][2], bff[4][2];
#pragma unroll
    for (int m = 0; m < 4; ++m)
#pragma unroll
      for (int ks = 0; ks < 2; ++ks)
        af[m][ks] = *reinterpret_cast<const bf16x8*>(
            &As[buf][(wm * 64 + m * 16 + l16) * 64 +
                     ((ks * 4 + g4) ^ xr) * 8]);
#pragma unroll
    for (int n = 0; n < 4; ++n)
#pragma unroll
      for (int ks = 0; ks < 2; ++ks)
        bff[n][ks] = *reinterpret_cast<const bf16x8*>(
            &Bs[buf][(wn * 64 + n * 16 + l16) * 64 +
                     ((ks * 4 + g4) ^ xr) * 8]);

    if (t + 2 < tiles) stage(t + 2);

    __builtin_amdgcn_s_setprio(1);
#pragma unroll
    for (int m = 0; m < 4; ++m)
#pragma unroll
      for (int n = 0; n < 4; ++n)
#pragma unroll
        for (int ks = 0; ks < 2; ++ks)
          acc[m][n] = __builtin_amdgcn_mfma_f32_16x16x32_bf16(
              af[m][ks], bff[n][ks], acc[m][n], 0, 0, 0);
    __builtin_amdgcn_s_setprio(0);

    if (t + 2 < tiles)
      asm volatile("s_waitcnt vmcnt(6)" ::: "memory");
    else
      asm volatile("s_waitcnt vmcnt(0)" ::: "memory");
    __builtin_amdgcn_s_barrier();
    __builtin_amdgcn_sched_barrier(0);
  }

#pragma unroll
  for (int m = 0; m < 4; ++m)
#pragma unroll
    for (int n = 0; n < 4; ++n)
#pragma unroll
      for (int r = 0; r < 4; ++r) {
        int row = m0 + wm * 64 + m * 16 + g4 * 4 + r;
        int col = n0 + wn * 64 + n * 16 + l16;
        C[(size_t)row * N + col] = (OutT)acc[m][n][r];
      }
}

// ---------------------------------------------------------------------------
// Flash attention body: one 128-key step, K issued LATE (post-QK) so both K
// and V have a full-iteration prefetch lead with a single kf register set.
// P pack via v_perm_b32 (RTZ bf16, byte order explicit); row-sum l via
// ones-MFMA into acc_l (verified on-device in round 7) -- denominator is
// bf16-consistent with the PV numerator.
// ---------------------------------------------------------------------------
template <bool PRE>
__device__ __forceinline__ void attn_body(
    const bf16_t* kp_next, const bf16_t* vp_next, bf16_t* vst_next,
    unsigned vrd, uint32x4 (&kf)[2][2], const bf16x8 (&qf)[4][2],
    const bf16x8 vones, f32x4 (&acc_o)[16], f32x4 (&acc_l)[4]) {
  // ---- A. stage V(i+1) (wave-private, async, zero VGPR)
  if constexpr (PRE) {
#pragma unroll
    for (int t = 0; t < 4; ++t)
      gload_lds16(vp_next + t * 16, vst_next + t * 512);
  }

  // ---- B. V(i) landed (issued one body earlier; V older than K)
  if constexpr (PRE)
    asm volatile("s_waitcnt vmcnt(8)" ::: "memory");
  else
    asm volatile("s_waitcnt vmcnt(4)" ::: "memory");
  __builtin_amdgcn_sched_barrier(0);

  // ---- C. V(i) B-frags via HW transpose read (per-lane addr = base+lane*8)
  uint32x2 vr[4][2];
#define TRR(dst, OFFSTR)                              \
  asm volatile("ds_read_b64_tr_b16 %0, %1 offset:" OFFSTR \
               : "=v"(dst)                            \
               : "v"(vrd))
  TRR(vr[0][0], "0");    TRR(vr[0][1], "512");
  TRR(vr[1][0], "1024"); TRR(vr[1][1], "1536");
  TRR(vr[2][0], "2048"); TRR(vr[2][1], "2560");
  TRR(vr[3][0], "3072"); TRR(vr[3][1], "3584");
#undef TRR

  // ---- D. K(i) ready (issued one body earlier, full-iter lead)
  if constexpr (PRE)
    asm volatile("s_waitcnt vmcnt(4)" ::: "memory");
  else
    asm volatile("s_waitcnt vmcnt(0)" ::: "memory");
  __builtin_amdgcn_sched_barrier(0);  // rule 18

  // ---- E. swapped QK^T: s[key][q] (Q pre-scaled)
  f32x4 sA[4] = {}, sB[4] = {};
#pragma unroll
  for (int qb = 0; qb < 4; ++qb) {
    sA[qb] = __builtin_amdgcn_mfma_f32_16x16x32_bf16(
        __builtin_bit_cast(bf16x8, kf[0][0]), qf[qb][0], sA[qb], 0, 0, 0);
    sA[qb] = __builtin_amdgcn_mfma_f32_16x16x32_bf16(
        __builtin_bit_cast(bf16x8, kf[0][1]), qf[qb][1], sA[qb], 0, 0, 0);
    sB[qb] = __builtin_amdgcn_mfma_f32_16x16x32_bf16(
        __builtin_bit_cast(bf16x8, kf[1][0]), qf[qb][0], sB[qb], 0, 0, 0);
    sB[qb] = __builtin_amdgcn_mfma_f32_16x16x32_bf16(
        __builtin_bit_cast(bf16x8, kf[1][1]), qf[qb][1], sB[qb], 0, 0, 0);
  }

  // ---- F. issue K(i+1) into kf (registers dead after E)
  if constexpr (PRE) {
#pragma unroll
    for (int half = 0; half < 2; ++half)
#pragma unroll
      for (int kh = 0; kh < 2; ++kh)
        asm volatile("global_load_dwordx4 %0, %1, off"
                     : "=v"(kf[half][kh])
                     : "v"(kp_next + (size_t)half * 64 * RSQ + kh * 32)
                     : "memory");
  }

  // ---- G. exp2 -> v_perm_b32 pack (RTZ bf16; D = {lo=bf16(p_even),
  //      hi=bf16(p_odd)} via selector 0x07060302: bytes {S1.b2,S1.b3,
  //      S0.b2,S0.b3}, S1 = even operand)
  const unsigned psel = 0x07060302u;
  bf16x8 pf[4];
#pragma unroll
  for (int qb = 0; qb < 4; ++qb) {
    unsigned b0 = __builtin_bit_cast(unsigned, __builtin_amdgcn_exp2f(sA[qb][0]));
    unsigned b1 = __builtin_bit_cast(unsigned, __builtin_amdgcn_exp2f(sA[qb][1]));
    unsigned b2 = __builtin_bit_cast(unsigned, __builtin_amdgcn_exp2f(sA[qb][2]));
    unsigned b3 = __builtin_bit_cast(unsigned, __builtin_amdgcn_exp2f(sA[qb][3]));
    unsigned b4 = __builtin_bit_cast(unsigned, __builtin_amdgcn_exp2f(sB[qb][0]));
    unsigned b5 = __builtin_bit_cast(unsigned, __builtin_amdgcn_exp2f(sB[qb][1]));
    unsigned b6 = __builtin_bit_cast(unsigned, __builtin_amdgcn_exp2f(sB[qb][2]));
    unsigned b7 = __builtin_bit_cast(unsigned, __builtin_amdgcn_exp2f(sB[qb][3]));
    unsigned u0, u1, u2, u3;
    asm("v_perm_b32 %0, %1, %2, %3" : "=v"(u0) : "v"(b1), "v"(b0), "v"(psel));
    asm("v_perm_b32 %0, %1, %2, %3" : "=v"(u1) : "v"(b3), "v"(b2), "v"(psel));
    asm("v_perm_b32 %0, %1, %2, %3" : "=v"(u2) : "v"(b5), "v"(b4), "v"(psel));
    asm("v_perm_b32 %0, %1, %2, %3" : "=v"(u3) : "v"(b7), "v"(b6), "v"(psel));
    uint32x4 pu = {u0, u1, u2, u3};
    pf[qb] = __builtin_bit_cast(bf16x8, pu);
  }

  // ---- H. tr_reads complete; build vf; l via ones-MFMA + PV
  asm volatile("s_waitcnt lgkmcnt(0)" ::: "memory");
  __builtin_amdgcn_sched_barrier(0);
  bf16x8 vf[4];
#pragma unroll
  for (int db = 0; db < 4; ++db) {
    uint32x4 c = {vr[db][0].x, vr[db][0].y, vr[db][1].x, vr[db][1].y};
    vf[db] = __builtin_bit_cast(bf16x8, c);
  }
#pragma unroll
  for (int qb = 0; qb < 4; ++qb) {
    acc_l[qb] = __builtin_amdgcn_mfma_f32_16x16x32_bf16(
        pf[qb], vones, acc_l[qb], 0, 0, 0);
#pragma unroll
    for (int db = 0; db < 4; ++db)
      acc_o[qb * 4 + db] = __builtin_amdgcn_mfma_f32_16x16x32_bf16(
          pf[qb], vf[db], acc_o[qb * 4 + db], 0, 0, 0);
  }
}

// ---------------------------------------------------------------------------
__global__ __launch_bounds__(256) void attn_kernel(
    const bf16_t* __restrict__ qkv, bf16_t* __restrict__ out) {
  __shared__ __align__(16) unsigned char smem[33792];
  bf16_t* Vlds = (bf16_t*)smem;            // [4 waves][2 bufs][2048] = 32 KiB
  float(*Obuf)[66] = (float(*)[66])smem;   // aliases Vlds (k-loop finished)
  float* lbuf = (float*)(smem + 32768);    // [4][64] floats

  const int tid = threadIdx.x;
  const int lane = tid & 63;
  const int wid = tid >> 6;
  const int l16 = lane & 15;
  const int g4 = lane >> 4;

  // XCD-aware decode: all 32 q-tiles of one (b,h) on one XCD
  const int D = blockIdx.x;
  const int g = ((D >> 8) << 3) + (D & 7);
  const int h = g & 15;
  const int b = g >> 4;
  const int q0 = ((D >> 3) & 31) * 64;

  const size_t base = (size_t)b * SEQ * RSQ;

  // ---- Q fragments (pre-scaled by 0.125*log2e via w_qkv), hoisted
  bf16x8 qf[4][2];
#pragma unroll
  for (int qb = 0; qb < 4; ++qb)
#pragma unroll
    for (int kh = 0; kh < 2; ++kh)
      qf[qb][kh] = __builtin_bit_cast(
          bf16x8, *reinterpret_cast<const uint4*>(
                      qkv + base + (size_t)(q0 + qb * 16 + l16) * RSQ + h * DH +
                      kh * 32 + g4 * 8));

  const bf16_t* kbase =
      qkv + base + (size_t)(wid * 16 + l16) * RSQ + DM + h * DH + g4 * 8;

  // V staging source (pre-swizzled: linear LDS == [db][eh][g4][j][l16])
  const int keyoff = ((lane >> 5) << 6) + wid * 16 + (((lane >> 3) & 3) << 2) +
                     ((lane >> 1) & 3);
  const bf16_t* vsrc =
      qkv + base + (size_t)keyoff * RSQ + 2 * DM + h * DH + (lane & 1) * 8;
  bf16_t* vwave = Vlds + wid * 4096;  // 2 buffers of 2048
  const unsigned vlane = lds_b32addr(vwave) + (lane << 3);

  bf16x8 vones;
#pragma unroll
  for (int e = 0; e < 8; ++e) vones[e] = (bf16_t)1.0f;

  f32x4 acc_o[16] = {};
  f32x4 acc_l[4] = {};
  uint32x4 kf[2][2];

  // ---- prologue: stage V(0) FIRST (must be older than K(0)), then K(0)
#pragma unroll
  for (int t = 0; t < 4; ++t) gload_lds16(vsrc + t * 16, vwave + t * 512);
#pragma unroll
  for (int half = 0; half < 2; ++half)
#pragma unroll
    for (int kh = 0; kh < 2; ++kh)
      asm volatile("global_load_dwordx4 %0, %1, off"
                   : "=v"(kf[half][kh])
                   : "v"(kbase + (size_t)half * 64 * RSQ + kh * 32)
                   : "memory");

  // ---- pipelined k-loop: bodies 0..14 prefetch K(i+1)/V(i+1); body 15 drains
  for (int i = 0; i < 15; ++i) {
    attn_body<true>(kbase + (size_t)(i + 1) * 128 * RSQ,
                    vsrc + (size_t)(i + 1) * 128 * RSQ,
                    vwave + ((i + 1) & 1) * 2048, vlane + (i & 1) * 4096, kf,
                    qf, vones, acc_o, acc_l);
  }
  attn_body<false>(nullptr, nullptr, nullptr, vlane + 4096, kf, qf, vones,
                   acc_o, acc_l);

  // ---- per-wave l partials (acc_l[qb][r] = l for q=qb*16+g4*4+r, any col)
  if (l16 == 0) {
#pragma unroll
    for (int qb = 0; qb < 4; ++qb)
#pragma unroll
      for (int r = 0; r < 4; ++r)
        lbuf[wid * 64 + qb * 16 + g4 * 4 + r] = acc_l[qb][r];
  }

  // ---- cross-wave O reduction (Obuf aliases Vlds; safe: vmem drained)
  for (int ph = 0; ph < 4; ++ph) {
    __syncthreads();
    if (wid == ph) {
#pragma unroll
      for (int qb = 0; qb < 4; ++qb)
#pragma unroll
        for (int db = 0; db < 4; ++db)
#pragma unroll
          for (int r = 0; r < 4; ++r) {
            int q = qb * 16 + g4 * 4 + r;
            int d = db * 16 + l16;
            if (ph == 0)
              Obuf[q][d] = acc_o[qb * 4 + db][r];
            else
              Obuf[q][d] += acc_o[qb * 4 + db][r];
          }
    }
  }
  __syncthreads();

  // ---- epilogue
  {
    int q = wid * 16 + l16;
    float l = lbuf[0 * 64 + q] + lbuf[1 * 64 + q] + lbuf[2 * 64 + q] +
              lbuf[3 * 64 + q];
    float inv = 1.f / l;
    bf16_t ob[16];
#pragma unroll
    for (int c = 0; c < 16; ++c)
      ob[c] = (bf16_t)(Obuf[q][g4 * 16 + c] * inv);
    bf16_t* op = out + (size_t)(b * SEQ + q0 + q) * DM + h * DH + g4 * 16;
    *reinterpret_cast<uint4*>(op) = *reinterpret_cast<const uint4*>(&ob[0]);
    *reinterpret_cast<uint4*>(op + 8) = *reinterpret_cast<const uint4*>(&ob[8]);
  }
}

// ---------------------------------------------------------------------------
extern "C" void kernel_launch(void* const* d_in, const int* in_sizes, int n_in,
                              void* d_out, int out_size, void* d_ws, size_t ws_size,
                              hipStream_t stream) {
  const float* x = (const float*)d_in[0];       // [4,2048,1024] fp32
  const float* w_qkv = (const float*)d_in[1];   // [1024,3072] fp32
  const float* w_o = (const float*)d_in[2];     // [1024,1024] fp32
  float* out = (float*)d_out;                   // [4,2048,1024] fp32

  bf16_t* xb = (bf16_t*)d_ws;                        // [8192][1024]
  bf16_t* wqkvt = xb + (size_t)8192 * 1024;          // [3072][1024]
  bf16_t* wot = wqkvt + (size_t)3072 * 1024;         // [1024][1024]
  bf16_t* qkv = wot + (size_t)1024 * 1024;           // [8192][3072]
  bf16_t* attn = qkv + (size_t)8192 * 3072;          // [8192][1024]

  const float c_exp2 = 0.18033688011112042f;  // 0.125 * log2(e)

  f32_to_bf16_kernel<<<8192, 256, 0, stream>>>(x, xb, 8192 * 1024);
  transpose_f32_bf16_kernel<<<dim3(3072 / 32, 1024 / 32), 256, 0, stream>>>(
      w_qkv, wqkvt, 1024, 3072, 1024, c_exp2);
  transpose_f32_bf16_kernel<<<dim3(1024 / 32, 1024 / 32), 256, 0, stream>>>(
      w_o, wot, 1024, 1024, 0, 1.0f);

  // qkv = x @ w_qkv : 64x12 = 768 blocks (3 exact CU rounds)
  gemm_dp_kernel<bf16_t><<<768, 512, 0, stream>>>(
      xb, wqkvt, qkv, 8192, 3072, 1024, 12);
  attn_kernel<<<2048, 256, 0, stream>>>(qkv, attn);
  // out = attn @ w_o : 64x4 = 256 blocks (1 exact CU round)
  gemm_dp_kernel<float><<<256, 512, 0, stream>>>(
      attn, wot, out, 8192, 1024, 1024, 4);
}